// Round 6
// baseline (1109.998 us; speedup 1.0000x reference)
//
#include <hip/hip_runtime.h>
#include <hip/hip_bf16.h>
#include <math.h>

typedef __hip_bfloat16 bf16;
typedef unsigned short ushort_t;
typedef unsigned long long ull_t;
typedef __attribute__((ext_vector_type(8))) short short8;
typedef __attribute__((ext_vector_type(4))) float f32x4;

constexpr int NB = 128;      // batch
constexpr int NT = 256;      // time
constexpr int HCAT = 1024;   // 512+256+256
// padded K for bf16 GEMM operands (multiples of 64)
constexpr int KP0 = 320;     // 300
constexpr int KP1 = 128;     // 74
constexpr int KP2 = 64;      // 35

__device__ inline float bf2f(ushort_t u) {
  union { unsigned i; float f; } x; x.i = (unsigned)u << 16; return x.f;
}
__device__ inline ushort_t f2bf(float f) {
  bf16 b = __float2bfloat16(f);
  return *reinterpret_cast<ushort_t*>(&b);
}
// fast sigmoid/tanh via v_exp + v_rcp; saturate correctly at +-inf, no NaN.
__device__ inline float fsig(float x) {
  return __builtin_amdgcn_rcpf(1.f + __expf(-x));
}
__device__ inline float ftanh(float x) {
  return 2.f * __builtin_amdgcn_rcpf(1.f + __expf(-2.f * x)) - 1.f;
}

// ---------------------------------------------------------------------------
// weight convert: fp32 [R][K] -> bf16 [R][KP], zero-padded
// ---------------------------------------------------------------------------
__global__ __launch_bounds__(256) void k_cvt_w(
    const float* __restrict__ in, ushort_t* __restrict__ out, int R, int K, int KP)
{
  int i = blockIdx.x * 256 + threadIdx.x;
  if (i >= R * KP) return;
  int r = i / KP, k = i - r * KP;
  out[i] = (k < K) ? f2bf(in[(size_t)r * K + k]) : (ushort_t)0;
}

// ---------------------------------------------------------------------------
// x convert: fp32 x[B][NT][d] -> bf16 [rows][KP] (row = b*TC+tl), zero-padded
// ---------------------------------------------------------------------------
__global__ __launch_bounds__(256) void k_cvt_x(
    const float* __restrict__ x, ushort_t* __restrict__ out,
    int d, int KP, int t0, int tcShift, int total)
{
  int i = blockIdx.x * 256 + threadIdx.x;
  if (i >= total) return;
  int row = i / KP, k = i - row * KP;
  int b = row >> tcShift, tl = row & ((1 << tcShift) - 1);
  out[i] = (k < d) ? f2bf(x[((size_t)b * NT + t0 + tl) * d + k]) : (ushort_t)0;
}

// ---------------------------------------------------------------------------
// Generic bf16 B^T GEMM (R9-proven): 64x64 tile, BK=64, dbuf LDS, 1 barrier
// per chunk. mode 0: bf16 out + bias0+bias1 (gx). mode 1: fp32 relu (fc1).
// ---------------------------------------------------------------------------
__global__ __launch_bounds__(256) void k_gemm(
    const ushort_t* __restrict__ A, const ushort_t* __restrict__ B, int KP,
    const float* __restrict__ bias0, const float* __restrict__ bias1,
    ushort_t* __restrict__ outb, float* __restrict__ outf, int ldc, int mode)
{
  __shared__ ushort_t As[2][64][72];
  __shared__ ushort_t Bs[2][64][72];
  const int row0 = blockIdx.x * 64;
  const int col0 = blockIdx.y * 64;
  const int tid  = threadIdx.x;
  const int lane = tid & 63;
  const int w    = tid >> 6;
  const int n    = lane & 15;
  const int quad = lane >> 4;
  const int sr = tid >> 2;           // staging row 0..63
  const int sc = (tid & 3) * 16;     // staging col (elems)

  const ushort_t* arow = A + (size_t)(row0 + sr) * KP + sc;
  const ushort_t* brow = B + (size_t)(col0 + sr) * KP + sc;

  short8 ra0 = *reinterpret_cast<const short8*>(arow);
  short8 ra1 = *reinterpret_cast<const short8*>(arow + 8);
  short8 rb0 = *reinterpret_cast<const short8*>(brow);
  short8 rb1 = *reinterpret_cast<const short8*>(brow + 8);
  *reinterpret_cast<short8*>(&As[0][sr][sc])     = ra0;
  *reinterpret_cast<short8*>(&As[0][sr][sc + 8]) = ra1;
  *reinterpret_cast<short8*>(&Bs[0][sr][sc])     = rb0;
  *reinterpret_cast<short8*>(&Bs[0][sr][sc + 8]) = rb1;

  f32x4 acc[4] = {{0,0,0,0},{0,0,0,0},{0,0,0,0},{0,0,0,0}};
  const int nch = KP >> 6;
  for (int ch = 0; ch < nch; ++ch) {
    __syncthreads();
    const int cur = ch & 1;
    if (ch + 1 < nch) {
      const ushort_t* an = arow + (ch + 1) * 64;
      const ushort_t* bn = brow + (ch + 1) * 64;
      ra0 = *reinterpret_cast<const short8*>(an);
      ra1 = *reinterpret_cast<const short8*>(an + 8);
      rb0 = *reinterpret_cast<const short8*>(bn);
      rb1 = *reinterpret_cast<const short8*>(bn + 8);
    }
#pragma unroll
    for (int kc = 0; kc < 2; ++kc) {
      short8 bfr = *reinterpret_cast<const short8*>(&Bs[cur][w * 16 + n][quad * 8 + kc * 32]);
#pragma unroll
      for (int mt = 0; mt < 4; ++mt) {
        short8 afr = *reinterpret_cast<const short8*>(&As[cur][mt * 16 + n][quad * 8 + kc * 32]);
        acc[mt] = __builtin_amdgcn_mfma_f32_16x16x32_bf16(afr, bfr, acc[mt], 0, 0, 0);
      }
    }
    if (ch + 1 < nch) {
      const int nxt = 1 - cur;
      *reinterpret_cast<short8*>(&As[nxt][sr][sc])     = ra0;
      *reinterpret_cast<short8*>(&As[nxt][sr][sc + 8]) = ra1;
      *reinterpret_cast<short8*>(&Bs[nxt][sr][sc])     = rb0;
      *reinterpret_cast<short8*>(&Bs[nxt][sr][sc + 8]) = rb1;
    }
  }

  const int col = col0 + w * 16 + n;
  if (mode == 0) {
    const float bsum = bias0[col] + bias1[col];
#pragma unroll
    for (int mt = 0; mt < 4; ++mt)
#pragma unroll
      for (int r = 0; r < 4; ++r) {
        int row = row0 + mt * 16 + quad * 4 + r;
        outb[(size_t)row * ldc + col] = f2bf(acc[mt][r] + bsum);
      }
  } else {
    const float bsum = bias0[col];
#pragma unroll
    for (int mt = 0; mt < 4; ++mt)
#pragma unroll
      for (int r = 0; r < 4; ++r) {
        int row = row0 + mt * 16 + quad * 4 + r;
        outf[(size_t)row * ldc + col] = fmaxf(acc[mt][r] + bsum, 0.f);
      }
  }
}

// ---------------------------------------------------------------------------
// fc2 + log_softmax: one wave per chunk row; map chunk row -> global (b,t)
// ---------------------------------------------------------------------------
__global__ __launch_bounds__(256) void k_fc2(
    const float* __restrict__ Z, const float* __restrict__ W2,
    const float* __restrict__ b2, float* __restrict__ out, int t0, int tcShift)
{
  const int wave = threadIdx.x >> 6;
  const int lane = threadIdx.x & 63;
  const int bt = blockIdx.x * 4 + wave;
  const float* z = Z + (size_t)bt * 256;
  float zv[4];
#pragma unroll
  for (int j = 0; j < 4; ++j) zv[j] = z[lane + 64 * j];
  float lg[7];
#pragma unroll
  for (int o = 0; o < 7; ++o) {
    float a = 0.f;
#pragma unroll
    for (int j = 0; j < 4; ++j) a += zv[j] * W2[o * 256 + lane + 64 * j];
#pragma unroll
    for (int off = 32; off > 0; off >>= 1) a += __shfl_down(a, off, 64);
    lg[o] = a;   // valid on lane 0
  }
  if (lane == 0) {
    const int b = bt >> tcShift;
    const int tl = bt & ((1 << tcShift) - 1);
    float* op = out + ((size_t)b * NT + t0 + tl) * 7;
    float lo[7];
    float m = -1e30f;
#pragma unroll
    for (int o = 0; o < 7; ++o) { lo[o] = lg[o] + b2[o]; m = fmaxf(m, lo[o]); }
    float s = 0.f;
#pragma unroll
    for (int o = 0; o < 7; ++o) s += expf(lo[o] - m);
    float lse = m + logf(s);
#pragma unroll
    for (int o = 0; o < 7; ++o) op[o] = lo[o] - lse;
  }
}

// ---------------------------------------------------------------------------
// Recurrent kernel R15 = R11 (proven 920us protocol, verbatim) + one change:
// gx(t+1) prefetch moved from the epilogue to the TOP of the step (right
// after the poll passes), loaded as RAW u16 bits (converted at use). Why:
// vmcnt retires in issue order, so the sweep's check needs vmcnt(0) — it
// drains every older outstanding load. In R11 the 16 gx loads (HBM ~900cy)
// were issued ~200cy before the sweep, so every step's check stalled on
// them. Issued a full step (~2000cy) before use/drain, they are always
// complete — their latency leaves the serial chain. The asm memory fence
// pins the loads after the poll loop (LICM would otherwise hoist them
// above the sweep and reintroduce the stall).
// ---------------------------------------------------------------------------
template<int HL>
__device__ void lstm_body(const float* __restrict__ Whh,
                          const ushort_t* __restrict__ gx,   // bf16 bits, [NB][TC][4*HL]
                          unsigned* __restrict__ hb2,        // u32 [2][NB][HCAT] = epoch|bf16
                          float* __restrict__ cbuf,          // fp32 [NB][HCAT]
                          ushort_t* __restrict__ hs,         // bf16 [NB][TC][HCAT]
                          ushort_t* htile,                   // LDS [16][HL+8]
                          float (*gbuf)[16][34],             // LDS gate tiles
                          int g, int u0, int hoff, int t0, int TC)
{
  constexpr int KC  = HL / 32;
  constexpr int LHP = HL + 8;          // padded LDS row, bf16 units
  constexpr int NGR = HL / 32;         // 8-byte source granules per thread
  const int tid  = threadIdx.x;
  const int lane = tid & 63;
  const int wgate = tid >> 6;          // wave index == gate (i,f,g,o)
  const int n    = lane & 15;
  const int quad = lane >> 4;

  short8 wfrag[2][KC];
#pragma unroll
  for (int tau = 0; tau < 2; ++tau) {
    const float* wrow = Whh + ((size_t)wgate * HL + u0 + 16 * tau + n) * HL + quad * 8;
#pragma unroll
    for (int kc = 0; kc < KC; ++kc) {
      short8 f;
#pragma unroll
      for (int j = 0; j < 8; ++j) f[j] = (short)f2bf(wrow[kc * 32 + j]);
      wfrag[tau][kc] = f;
    }
  }

  const int u  = tid & 31;
  const int bh = tid >> 5;             // 0..7
  const int bb0 = g * 16 + bh;
  const int bb1 = bb0 + 8;
  const int hcol = hoff + u0 + u;
  float c0 = cbuf[(size_t)bb0 * HCAT + hcol];
  float c1 = cbuf[(size_t)bb1 * HCAT + hcol];

  const int srow = wgate * 4 + (lane >> 4);   // 0..15
  const int scol = lane & 15;
  unsigned* htile32 = reinterpret_cast<unsigned*>(htile);

  const size_t G4 = (size_t)(4 * HL);
  // raw bf16 bits of gx(t): converted only at use, so the load's wait point
  // is one full step after issue (always complete).
  ushort_t gxr0[4], gxr1[4];
#pragma unroll
  for (int q = 0; q < 4; ++q) {
    gxr0[q] = gx[((size_t)bb0 * TC) * G4 + (size_t)q * HL + u0 + u];
    gxr1[q] = gx[((size_t)bb1 * TC) * G4 + (size_t)q * HL + u0 + u];
  }

  const ull_t EPM = 0xFFFF0000FFFF0000ull;

  for (int t = 0; t < TC; ++t) {
    const unsigned ep = (unsigned)(t0 + t);
    const ull_t want = ((ull_t)ep << 16) | ((ull_t)ep << 48);
    const ull_t* src64 = reinterpret_cast<const ull_t*>(
        hb2 + ((size_t)(ep & 1) * NB + g * 16 + srow) * HCAT + hoff);

    // per-thread poll: loads return payload+epoch together; a sweep issues all
    // NGR loads back-to-back (waits batched), so one sweep costs ~1 LLC latency
    ull_t vv[NGR];
    while (true) {
#pragma unroll
      for (int i = 0; i < NGR; ++i)
        vv[i] = __hip_atomic_load(src64 + scol + i * 16,
                                  __ATOMIC_RELAXED, __HIP_MEMORY_SCOPE_AGENT);
      ull_t bad = 0;
#pragma unroll
      for (int i = 0; i < NGR; ++i) bad |= (vv[i] ^ want) & EPM;
      if (bad == 0) break;
      __builtin_amdgcn_s_sleep(1);
    }

    // gx(t+1) prefetch, pinned AFTER the poll (fence blocks LICM hoisting).
    // Raw u16 loads; HBM latency is fully covered by this step's compute.
    const bool pf = (t + 1 < TC);
    ushort_t gxn0[4], gxn1[4];
    asm volatile("" ::: "memory");
    if (pf) {
#pragma unroll
      for (int q = 0; q < 4; ++q) {
        gxn0[q] = gx[((size_t)bb0 * TC + t + 1) * G4 + (size_t)q * HL + u0 + u];
        gxn1[q] = gx[((size_t)bb1 * TC + t + 1) * G4 + (size_t)q * HL + u0 + u];
      }
    }

#pragma unroll
    for (int i = 0; i < NGR; ++i)
      htile32[srow * (LHP / 2) + scol + i * 16] =
          (unsigned)(vv[i] & 0xffffu) | ((unsigned)(vv[i] >> 16) & 0xffff0000u);
    __syncthreads();   // htile complete (also orders prev-step gbuf reads vs writes)

    f32x4 acc0 = {0.f, 0.f, 0.f, 0.f};
    f32x4 acc1 = {0.f, 0.f, 0.f, 0.f};
#pragma unroll
    for (int kc = 0; kc < KC; ++kc) {
      short8 a = *reinterpret_cast<const short8*>(htile + n * LHP + quad * 8 + kc * 32);
      acc0 = __builtin_amdgcn_mfma_f32_16x16x32_bf16(a, wfrag[0][kc], acc0, 0, 0, 0);
      acc1 = __builtin_amdgcn_mfma_f32_16x16x32_bf16(a, wfrag[1][kc], acc1, 0, 0, 0);
    }
#pragma unroll
    for (int r = 0; r < 4; ++r) {
      gbuf[wgate][quad * 4 + r][n]      = acc0[r];
      gbuf[wgate][quad * 4 + r][16 + n] = acc1[r];
    }
    __syncthreads();   // gbuf ready (also ensures all htile reads done)

    float pi0 = gbuf[0][bh][u] + bf2f(gxr0[0]);
    float pf0 = gbuf[1][bh][u] + bf2f(gxr0[1]);
    float pg0 = gbuf[2][bh][u] + bf2f(gxr0[2]);
    float po0 = gbuf[3][bh][u] + bf2f(gxr0[3]);
    float pi1 = gbuf[0][bh + 8][u] + bf2f(gxr1[0]);
    float pf1 = gbuf[1][bh + 8][u] + bf2f(gxr1[1]);
    float pg1 = gbuf[2][bh + 8][u] + bf2f(gxr1[2]);
    float po1 = gbuf[3][bh + 8][u] + bf2f(gxr1[3]);

    float si0 = fsig(pi0), sf0 = fsig(pf0), so0 = fsig(po0);
    float tg0 = ftanh(pg0);
    c0 = sf0 * c0 + si0 * tg0;
    float h0 = so0 * ftanh(c0);
    float si1 = fsig(pi1), sf1 = fsig(pf1), so1 = fsig(po1);
    float tg1 = ftanh(pg1);
    c1 = sf1 * c1 + si1 * tg1;
    float h1 = so1 * ftanh(c1);

    // publish h(t+1): payload and validity in one atomic 4B word — no fence,
    // no drain, no flag. Issued immediately; everything after is off-path.
    const ushort_t hb0 = f2bf(h0), hb1 = f2bf(h1);
    const unsigned ep1 = (ep + 1) << 16;
    unsigned* nxt = hb2 + (size_t)((ep + 1) & 1) * NB * HCAT;
    __hip_atomic_store(nxt + (size_t)bb0 * HCAT + hcol, ep1 | (unsigned)hb0,
                       __ATOMIC_RELAXED, __HIP_MEMORY_SCOPE_AGENT);
    __hip_atomic_store(nxt + (size_t)bb1 * HCAT + hcol, ep1 | (unsigned)hb1,
                       __ATOMIC_RELAXED, __HIP_MEMORY_SCOPE_AGENT);

    // off-critical-path: hs stores
    hs[((size_t)bb0 * TC + t) * HCAT + hcol] = hb0;
    hs[((size_t)bb1 * TC + t) * HCAT + hcol] = hb1;

    // rotate prefetched gx into the live regs (loads long complete by now)
    if (pf) {
#pragma unroll
      for (int q = 0; q < 4; ++q) { gxr0[q] = gxn0[q]; gxr1[q] = gxn1[q]; }
    }
  }
  cbuf[(size_t)bb0 * HCAT + hcol] = c0;
  cbuf[(size_t)bb1 * HCAT + hcol] = c1;
}

__global__ __launch_bounds__(256, 1) void k_lstm(
    const float* __restrict__ Whh0, const float* __restrict__ Whh1,
    const float* __restrict__ Whh2,
    const ushort_t* __restrict__ gx0, const ushort_t* __restrict__ gx1,
    const ushort_t* __restrict__ gx2,
    unsigned* __restrict__ hb2, float* __restrict__ cbuf,
    ushort_t* __restrict__ hs,
    int t0, int TC)
{
  __shared__ ushort_t htile[16 * 520];
  __shared__ float gbuf[4][16][34];
  const int g    = blockIdx.x & 7;
  const int rank = blockIdx.x >> 3;        // 0..31
  if (rank < 16) {
    lstm_body<512>(Whh0, gx0, hb2, cbuf, hs, htile, gbuf,
                   g, rank * 32, 0, t0, TC);
  } else if (rank < 24) {
    lstm_body<256>(Whh1, gx1, hb2, cbuf, hs, htile, gbuf,
                   g, (rank - 16) * 32, 512, t0, TC);
  } else {
    lstm_body<256>(Whh2, gx2, hb2, cbuf, hs, htile, gbuf,
                   g, (rank - 24) * 32, 768, t0, TC);
  }
}

// fallback if workspace is too small: distinctive sentinel
__global__ void k_fill(float* __restrict__ out, int n, float v) {
  int i = blockIdx.x * 256 + threadIdx.x;
  if (i < n) out[i] = v;
}

extern "C" void kernel_launch(void* const* d_in, const int* in_sizes, int n_in,
                              void* d_out, int out_size, void* d_ws, size_t ws_size,
                              hipStream_t stream) {
  (void)in_sizes; (void)n_in;
  const float* x0  = (const float*)d_in[0];
  const float* x1  = (const float*)d_in[1];
  const float* x2  = (const float*)d_in[2];
  const float* Wih0 = (const float*)d_in[3];
  const float* Whh0 = (const float*)d_in[4];
  const float* bih0 = (const float*)d_in[5];
  const float* bhh0 = (const float*)d_in[6];
  const float* Wih1 = (const float*)d_in[7];
  const float* Whh1 = (const float*)d_in[8];
  const float* bih1 = (const float*)d_in[9];
  const float* bhh1 = (const float*)d_in[10];
  const float* Wih2 = (const float*)d_in[11];
  const float* Whh2 = (const float*)d_in[12];
  const float* bih2 = (const float*)d_in[13];
  const float* bhh2 = (const float*)d_in[14];
  const float* W1 = (const float*)d_in[15];
  const float* b1 = (const float*)d_in[16];
  const float* W2 = (const float*)d_in[17];
  const float* b2 = (const float*)d_in[18];
  float* out = (float*)d_out;

  const size_t szHbuf  = (size_t)2 * NB * HCAT * 4;   // u32 epoch|bf16, dbuf
  const size_t szCbuf  = (size_t)NB * HCAT * 4;
  const size_t szWb0   = (size_t)2048 * KP0 * 2;
  const size_t szWb1   = (size_t)1024 * KP1 * 2;
  const size_t szWb2   = (size_t)1024 * KP2 * 2;
  const size_t szW1b   = (size_t)256 * 1024 * 2;

  const int cands[6] = {256, 128, 64, 32, 16, 8};
  int TC = 0;
  for (int ci = 0; ci < 6; ++ci) {
    int tc = cands[ci];
    size_t rows = (size_t)NB * tc;
    size_t o = 0;
    auto al = [&](size_t bytes) { o += (bytes + 255) & ~(size_t)255; };
    al(szHbuf); al(szCbuf);
    al(szWb0); al(szWb1); al(szWb2); al(szW1b);
    al(rows * HCAT * 2);                // hs chunk
    al(rows * 256 * 4);                 // z chunk
    al(rows * 2048 * 2);                // gx0 chunk
    al(rows * 1024 * 2);                // gx1 chunk
    al(rows * 1024 * 2);                // gx2 chunk
    al(rows * KP0 * 2);                 // xb0
    al(rows * KP1 * 2);                 // xb1
    al(rows * KP2 * 2);                 // xb2
    if (o <= ws_size) { TC = tc; break; }
  }
  if (TC == 0) {
    k_fill<<<dim3((out_size + 255) / 256), dim3(256), 0, stream>>>(out, out_size, -8888.f);
    return;
  }
  const int tcShift = __builtin_ctz(TC);
  const size_t rows = (size_t)NB * TC;

  char* ws = (char*)d_ws;
  size_t off = 0;
  auto alloc = [&](size_t bytes) -> void* {
    void* p = ws + off;
    off += (bytes + 255) & ~(size_t)255;
    return p;
  };
  unsigned* hb2  = (unsigned*)alloc(szHbuf);
  float* cbuf    = (float*)alloc(szCbuf);
  size_t staticEnd = off;
  ushort_t* wb0  = (ushort_t*)alloc(szWb0);
  ushort_t* wb1  = (ushort_t*)alloc(szWb1);
  ushort_t* wb2  = (ushort_t*)alloc(szWb2);
  ushort_t* w1b  = (ushort_t*)alloc(szW1b);
  ushort_t* hs   = (ushort_t*)alloc(rows * HCAT * 2);
  float* z       = (float*)alloc(rows * 256 * 4);
  ushort_t* gx0  = (ushort_t*)alloc(rows * 2048 * 2);
  ushort_t* gx1  = (ushort_t*)alloc(rows * 1024 * 2);
  ushort_t* gx2  = (ushort_t*)alloc(rows * 1024 * 2);
  ushort_t* xb0  = (ushort_t*)alloc(rows * KP0 * 2);
  ushort_t* xb1  = (ushort_t*)alloc(rows * KP1 * 2);
  ushort_t* xb2  = (ushort_t*)alloc(rows * KP2 * 2);

  hipMemsetAsync(ws, 0, staticEnd, stream);   // epoch 0 == h(0) == 0, c(0) == 0

  dim3 blk(256);
  k_cvt_w<<<dim3((2048 * KP0 + 255) / 256), blk, 0, stream>>>(Wih0, wb0, 2048, 300, KP0);
  k_cvt_w<<<dim3((1024 * KP1 + 255) / 256), blk, 0, stream>>>(Wih1, wb1, 1024, 74, KP1);
  k_cvt_w<<<dim3((1024 * KP2 + 255) / 256), blk, 0, stream>>>(Wih2, wb2, 1024, 35, KP2);
  k_cvt_w<<<dim3((256 * 1024 + 255) / 256), blk, 0, stream>>>(W1, w1b, 256, 1024, 1024);

  const int rb = (int)(rows / 64);   // row-blocks per chunk
  for (int t0 = 0; t0 < NT; t0 += TC) {
    int tot0 = (int)(rows * KP0), tot1 = (int)(rows * KP1), tot2 = (int)(rows * KP2);
    k_cvt_x<<<dim3((tot0 + 255) / 256), blk, 0, stream>>>(x0, xb0, 300, KP0, t0, tcShift, tot0);
    k_cvt_x<<<dim3((tot1 + 255) / 256), blk, 0, stream>>>(x1, xb1, 74, KP1, t0, tcShift, tot1);
    k_cvt_x<<<dim3((tot2 + 255) / 256), blk, 0, stream>>>(x2, xb2, 35, KP2, t0, tcShift, tot2);

    k_gemm<<<dim3(rb, 2048 / 64), blk, 0, stream>>>(xb0, wb0, KP0, bih0, bhh0, gx0, nullptr, 2048, 0);
    k_gemm<<<dim3(rb, 1024 / 64), blk, 0, stream>>>(xb1, wb1, KP1, bih1, bhh1, gx1, nullptr, 1024, 0);
    k_gemm<<<dim3(rb, 1024 / 64), blk, 0, stream>>>(xb2, wb2, KP2, bih2, bhh2, gx2, nullptr, 1024, 0);

    k_lstm<<<dim3(256), blk, 0, stream>>>(Whh0, Whh1, Whh2,
                                          gx0, gx1, gx2,
                                          hb2, cbuf, hs, t0, TC);

    k_gemm<<<dim3(rb, 256 / 64), blk, 0, stream>>>(hs, w1b, 1024, b1, nullptr, nullptr, z, 256, 1);
    k_fc2<<<dim3((int)(rows / 4)), blk, 0, stream>>>(z, W2, b2, out, t0, tcShift);
  }
}

// Round 7
// 1102.008 us; speedup vs baseline: 1.0073x; 1.0073x over previous
//
#include <hip/hip_runtime.h>
#include <hip/hip_bf16.h>
#include <math.h>

typedef __hip_bfloat16 bf16;
typedef unsigned short ushort_t;
typedef unsigned long long ull_t;
typedef __attribute__((ext_vector_type(8))) short short8;
typedef __attribute__((ext_vector_type(4))) float f32x4;

constexpr int NB = 128;      // batch
constexpr int NT = 256;      // time
constexpr int HCAT = 1024;   // 512+256+256
// padded K for bf16 GEMM operands (multiples of 64)
constexpr int KP0 = 320;     // 300
constexpr int KP1 = 128;     // 74
constexpr int KP2 = 64;      // 35

__device__ inline float bf2f(ushort_t u) {
  union { unsigned i; float f; } x; x.i = (unsigned)u << 16; return x.f;
}
__device__ inline ushort_t f2bf(float f) {
  bf16 b = __float2bfloat16(f);
  return *reinterpret_cast<ushort_t*>(&b);
}
// fast sigmoid/tanh via v_exp + v_rcp; saturate correctly at +-inf, no NaN.
__device__ inline float fsig(float x) {
  return __builtin_amdgcn_rcpf(1.f + __expf(-x));
}
__device__ inline float ftanh(float x) {
  return 2.f * __builtin_amdgcn_rcpf(1.f + __expf(-2.f * x)) - 1.f;
}

// ---------------------------------------------------------------------------
// weight convert: fp32 [R][K] -> bf16 [R][KP], zero-padded
// ---------------------------------------------------------------------------
__global__ __launch_bounds__(256) void k_cvt_w(
    const float* __restrict__ in, ushort_t* __restrict__ out, int R, int K, int KP)
{
  int i = blockIdx.x * 256 + threadIdx.x;
  if (i >= R * KP) return;
  int r = i / KP, k = i - r * KP;
  out[i] = (k < K) ? f2bf(in[(size_t)r * K + k]) : (ushort_t)0;
}

// ---------------------------------------------------------------------------
// x convert: fp32 x[B][NT][d] -> bf16 [rows][KP] (row = b*TC+tl), zero-padded
// ---------------------------------------------------------------------------
__global__ __launch_bounds__(256) void k_cvt_x(
    const float* __restrict__ x, ushort_t* __restrict__ out,
    int d, int KP, int t0, int tcShift, int total)
{
  int i = blockIdx.x * 256 + threadIdx.x;
  if (i >= total) return;
  int row = i / KP, k = i - row * KP;
  int b = row >> tcShift, tl = row & ((1 << tcShift) - 1);
  out[i] = (k < d) ? f2bf(x[((size_t)b * NT + t0 + tl) * d + k]) : (ushort_t)0;
}

// ---------------------------------------------------------------------------
// Generic bf16 B^T GEMM (R9-proven): 64x64 tile, BK=64, dbuf LDS, 1 barrier
// per chunk. mode 0: bf16 out + bias0+bias1 (gx). mode 1: fp32 relu (fc1).
// ---------------------------------------------------------------------------
__global__ __launch_bounds__(256) void k_gemm(
    const ushort_t* __restrict__ A, const ushort_t* __restrict__ B, int KP,
    const float* __restrict__ bias0, const float* __restrict__ bias1,
    ushort_t* __restrict__ outb, float* __restrict__ outf, int ldc, int mode)
{
  __shared__ ushort_t As[2][64][72];
  __shared__ ushort_t Bs[2][64][72];
  const int row0 = blockIdx.x * 64;
  const int col0 = blockIdx.y * 64;
  const int tid  = threadIdx.x;
  const int lane = tid & 63;
  const int w    = tid >> 6;
  const int n    = lane & 15;
  const int quad = lane >> 4;
  const int sr = tid >> 2;           // staging row 0..63
  const int sc = (tid & 3) * 16;     // staging col (elems)

  const ushort_t* arow = A + (size_t)(row0 + sr) * KP + sc;
  const ushort_t* brow = B + (size_t)(col0 + sr) * KP + sc;

  short8 ra0 = *reinterpret_cast<const short8*>(arow);
  short8 ra1 = *reinterpret_cast<const short8*>(arow + 8);
  short8 rb0 = *reinterpret_cast<const short8*>(brow);
  short8 rb1 = *reinterpret_cast<const short8*>(brow + 8);
  *reinterpret_cast<short8*>(&As[0][sr][sc])     = ra0;
  *reinterpret_cast<short8*>(&As[0][sr][sc + 8]) = ra1;
  *reinterpret_cast<short8*>(&Bs[0][sr][sc])     = rb0;
  *reinterpret_cast<short8*>(&Bs[0][sr][sc + 8]) = rb1;

  f32x4 acc[4] = {{0,0,0,0},{0,0,0,0},{0,0,0,0},{0,0,0,0}};
  const int nch = KP >> 6;
  for (int ch = 0; ch < nch; ++ch) {
    __syncthreads();
    const int cur = ch & 1;
    if (ch + 1 < nch) {
      const ushort_t* an = arow + (ch + 1) * 64;
      const ushort_t* bn = brow + (ch + 1) * 64;
      ra0 = *reinterpret_cast<const short8*>(an);
      ra1 = *reinterpret_cast<const short8*>(an + 8);
      rb0 = *reinterpret_cast<const short8*>(bn);
      rb1 = *reinterpret_cast<const short8*>(bn + 8);
    }
#pragma unroll
    for (int kc = 0; kc < 2; ++kc) {
      short8 bfr = *reinterpret_cast<const short8*>(&Bs[cur][w * 16 + n][quad * 8 + kc * 32]);
#pragma unroll
      for (int mt = 0; mt < 4; ++mt) {
        short8 afr = *reinterpret_cast<const short8*>(&As[cur][mt * 16 + n][quad * 8 + kc * 32]);
        acc[mt] = __builtin_amdgcn_mfma_f32_16x16x32_bf16(afr, bfr, acc[mt], 0, 0, 0);
      }
    }
    if (ch + 1 < nch) {
      const int nxt = 1 - cur;
      *reinterpret_cast<short8*>(&As[nxt][sr][sc])     = ra0;
      *reinterpret_cast<short8*>(&As[nxt][sr][sc + 8]) = ra1;
      *reinterpret_cast<short8*>(&Bs[nxt][sr][sc])     = rb0;
      *reinterpret_cast<short8*>(&Bs[nxt][sr][sc + 8]) = rb1;
    }
  }

  const int col = col0 + w * 16 + n;
  if (mode == 0) {
    const float bsum = bias0[col] + bias1[col];
#pragma unroll
    for (int mt = 0; mt < 4; ++mt)
#pragma unroll
      for (int r = 0; r < 4; ++r) {
        int row = row0 + mt * 16 + quad * 4 + r;
        outb[(size_t)row * ldc + col] = f2bf(acc[mt][r] + bsum);
      }
  } else {
    const float bsum = bias0[col];
#pragma unroll
    for (int mt = 0; mt < 4; ++mt)
#pragma unroll
      for (int r = 0; r < 4; ++r) {
        int row = row0 + mt * 16 + quad * 4 + r;
        outf[(size_t)row * ldc + col] = fmaxf(acc[mt][r] + bsum, 0.f);
      }
  }
}

// ---------------------------------------------------------------------------
// fc2 + log_softmax: one wave per chunk row; map chunk row -> global (b,t)
// ---------------------------------------------------------------------------
__global__ __launch_bounds__(256) void k_fc2(
    const float* __restrict__ Z, const float* __restrict__ W2,
    const float* __restrict__ b2, float* __restrict__ out, int t0, int tcShift)
{
  const int wave = threadIdx.x >> 6;
  const int lane = threadIdx.x & 63;
  const int bt = blockIdx.x * 4 + wave;
  const float* z = Z + (size_t)bt * 256;
  float zv[4];
#pragma unroll
  for (int j = 0; j < 4; ++j) zv[j] = z[lane + 64 * j];
  float lg[7];
#pragma unroll
  for (int o = 0; o < 7; ++o) {
    float a = 0.f;
#pragma unroll
    for (int j = 0; j < 4; ++j) a += zv[j] * W2[o * 256 + lane + 64 * j];
#pragma unroll
    for (int off = 32; off > 0; off >>= 1) a += __shfl_down(a, off, 64);
    lg[o] = a;   // valid on lane 0
  }
  if (lane == 0) {
    const int b = bt >> tcShift;
    const int tl = bt & ((1 << tcShift) - 1);
    float* op = out + ((size_t)b * NT + t0 + tl) * 7;
    float lo[7];
    float m = -1e30f;
#pragma unroll
    for (int o = 0; o < 7; ++o) { lo[o] = lg[o] + b2[o]; m = fmaxf(m, lo[o]); }
    float s = 0.f;
#pragma unroll
    for (int o = 0; o < 7; ++o) s += expf(lo[o] - m);
    float lse = m + logf(s);
#pragma unroll
    for (int o = 0; o < 7; ++o) op[o] = lo[o] - lse;
  }
}

// ---------------------------------------------------------------------------
// Recurrent kernel R16 = R11 verbatim + advisory flag gate.
// Diagnosis: R11's continuous sweep re-reads the full 16xHL epoch-word tile
// (32KB/block/round) -> ~28TB/s aggregate LLC demand from 256 polling blocks
// — saturates the memory-side cache; every sweep pays queueing delay, not
// just latency (explains the 3x gap vs the serial-chain model, and why R12's
// extra sweep cost +53%).
// Fix: producers ALSO store a per-(consumer,producer,wave) flag word (=ep+1)
// right after their data publishes — relaxed, NO drain/fence (per-wave flag
// follows that wave's own data stores in issue order). Consumers gate on ONE
// 64-lane load/round (their replicated 256B flag line) and only then run the
// unchanged R11 payload sweep with per-word epoch validation (correctness
// backstop for any flag/data visibility race; retry is rare). Steady poll
// LLC traffic drops 16x; no hot line (lines replicated per consumer).
// ---------------------------------------------------------------------------
template<int HL>
__device__ void lstm_body(const float* __restrict__ Whh,
                          const ushort_t* __restrict__ gx,   // bf16 bits, [NB][TC][4*HL]
                          unsigned* __restrict__ hb2,        // u32 [2][NB][HCAT] = epoch|bf16
                          float* __restrict__ cbuf,          // fp32 [NB][HCAT]
                          ushort_t* __restrict__ hs,         // bf16 [NB][TC][HCAT]
                          ushort_t* htile,                   // LDS [16][HL+8]
                          float (*gbuf)[16][34],             // LDS gate tiles
                          unsigned* fl,                      // flags [16 consumers][64 words]
                          int myblk, int nblk,
                          int g, int u0, int hoff, int t0, int TC)
{
  constexpr int KC  = HL / 32;
  constexpr int LHP = HL + 8;          // padded LDS row, bf16 units
  constexpr int NGR = HL / 32;         // 8-byte source granules per thread
  const int tid  = threadIdx.x;
  const int lane = tid & 63;
  const int wgate = tid >> 6;          // wave index == gate (i,f,g,o)
  const int n    = lane & 15;
  const int quad = lane >> 4;

  short8 wfrag[2][KC];
#pragma unroll
  for (int tau = 0; tau < 2; ++tau) {
    const float* wrow = Whh + ((size_t)wgate * HL + u0 + 16 * tau + n) * HL + quad * 8;
#pragma unroll
    for (int kc = 0; kc < KC; ++kc) {
      short8 f;
#pragma unroll
      for (int j = 0; j < 8; ++j) f[j] = (short)f2bf(wrow[kc * 32 + j]);
      wfrag[tau][kc] = f;
    }
  }

  const int u  = tid & 31;
  const int bh = tid >> 5;             // 0..7
  const int bb0 = g * 16 + bh;
  const int bb1 = bb0 + 8;
  const int hcol = hoff + u0 + u;
  float c0 = cbuf[(size_t)bb0 * HCAT + hcol];
  float c1 = cbuf[(size_t)bb1 * HCAT + hcol];

  const int srow = wgate * 4 + (lane >> 4);   // 0..15
  const int scol = lane & 15;
  unsigned* htile32 = reinterpret_cast<unsigned*>(htile);

  // flag addressing: own consumer line (nblk*4 valid words, 64-word stride);
  // producer side scatters ep+1 to flags[c][myblk*4+wgate] for c<nblk.
  const unsigned* flc = fl + (size_t)myblk * 64;
  const int fidx = lane & (nblk * 4 - 1);
  unsigned* fstore = fl + (size_t)lane * 64 + myblk * 4 + wgate;

  const size_t G4 = (size_t)(4 * HL);
  float gxv0[4], gxv1[4];
#pragma unroll
  for (int q = 0; q < 4; ++q) {
    gxv0[q] = bf2f(gx[((size_t)bb0 * TC) * G4 + (size_t)q * HL + u0 + u]);
    gxv1[q] = bf2f(gx[((size_t)bb1 * TC) * G4 + (size_t)q * HL + u0 + u]);
  }

  const ull_t EPM = 0xFFFF0000FFFF0000ull;

  for (int t = 0; t < TC; ++t) {
    const unsigned ep = (unsigned)(t0 + t);
    const ull_t want = ((ull_t)ep << 16) | ((ull_t)ep << 48);
    const ull_t* src64 = reinterpret_cast<const ull_t*>(
        hb2 + ((size_t)(ep & 1) * NB + g * 16 + srow) * HCAT + hoff);

    // flag gate: ONE 64-lane load per round (4 cache lines) instead of the
    // 32KB payload re-sweep. Advisory only — payload epochs are validated
    // below regardless.
    while (true) {
      unsigned fv = __hip_atomic_load(flc + fidx, __ATOMIC_RELAXED,
                                      __HIP_MEMORY_SCOPE_AGENT);
      if (__all((int)(fv >= ep))) break;
      __builtin_amdgcn_s_sleep(1);
    }

    // payload sweep (R11 verbatim): loads return payload+epoch together;
    // usually passes on the first round now.
    ull_t vv[NGR];
    while (true) {
#pragma unroll
      for (int i = 0; i < NGR; ++i)
        vv[i] = __hip_atomic_load(src64 + scol + i * 16,
                                  __ATOMIC_RELAXED, __HIP_MEMORY_SCOPE_AGENT);
      ull_t bad = 0;
#pragma unroll
      for (int i = 0; i < NGR; ++i) bad |= (vv[i] ^ want) & EPM;
      if (bad == 0) break;
      __builtin_amdgcn_s_sleep(1);
    }
#pragma unroll
    for (int i = 0; i < NGR; ++i)
      htile32[srow * (LHP / 2) + scol + i * 16] =
          (unsigned)(vv[i] & 0xffffu) | ((unsigned)(vv[i] >> 16) & 0xffff0000u);
    __syncthreads();   // htile complete (also orders prev-step gbuf reads vs writes)

    f32x4 acc0 = {0.f, 0.f, 0.f, 0.f};
    f32x4 acc1 = {0.f, 0.f, 0.f, 0.f};
#pragma unroll
    for (int kc = 0; kc < KC; ++kc) {
      short8 a = *reinterpret_cast<const short8*>(htile + n * LHP + quad * 8 + kc * 32);
      acc0 = __builtin_amdgcn_mfma_f32_16x16x32_bf16(a, wfrag[0][kc], acc0, 0, 0, 0);
      acc1 = __builtin_amdgcn_mfma_f32_16x16x32_bf16(a, wfrag[1][kc], acc1, 0, 0, 0);
    }
#pragma unroll
    for (int r = 0; r < 4; ++r) {
      gbuf[wgate][quad * 4 + r][n]      = acc0[r];
      gbuf[wgate][quad * 4 + r][16 + n] = acc1[r];
    }
    __syncthreads();   // gbuf ready (also ensures all htile reads done)

    float pi0 = gbuf[0][bh][u] + gxv0[0];
    float pf0 = gbuf[1][bh][u] + gxv0[1];
    float pg0 = gbuf[2][bh][u] + gxv0[2];
    float po0 = gbuf[3][bh][u] + gxv0[3];
    float pi1 = gbuf[0][bh + 8][u] + gxv1[0];
    float pf1 = gbuf[1][bh + 8][u] + gxv1[1];
    float pg1 = gbuf[2][bh + 8][u] + gxv1[2];
    float po1 = gbuf[3][bh + 8][u] + gxv1[3];

    float si0 = fsig(pi0), sf0 = fsig(pf0), so0 = fsig(po0);
    float tg0 = ftanh(pg0);
    c0 = sf0 * c0 + si0 * tg0;
    float h0 = so0 * ftanh(c0);
    float si1 = fsig(pi1), sf1 = fsig(pf1), so1 = fsig(po1);
    float tg1 = ftanh(pg1);
    c1 = sf1 * c1 + si1 * tg1;
    float h1 = so1 * ftanh(c1);

    // publish h(t+1): payload and validity in one atomic 4B word — no fence,
    // no drain, no flag ordering required (epoch words are ground truth).
    const ushort_t hb0 = f2bf(h0), hb1 = f2bf(h1);
    const unsigned ep1 = (ep + 1) << 16;
    unsigned* nxt = hb2 + (size_t)((ep + 1) & 1) * NB * HCAT;
    __hip_atomic_store(nxt + (size_t)bb0 * HCAT + hcol, ep1 | (unsigned)hb0,
                       __ATOMIC_RELAXED, __HIP_MEMORY_SCOPE_AGENT);
    __hip_atomic_store(nxt + (size_t)bb1 * HCAT + hcol, ep1 | (unsigned)hb1,
                       __ATOMIC_RELAXED, __HIP_MEMORY_SCOPE_AGENT);

    // advisory flag: this wave's data stores were issued just above; flag
    // follows them in issue order. Scattered 1-instruction store (lane<nblk
    // -> nblk distinct consumer lines). No drain.
    if (lane < nblk) {
      __hip_atomic_store(fstore, ep + 1, __ATOMIC_RELAXED,
                         __HIP_MEMORY_SCOPE_AGENT);
    }

    // off-critical-path: hs stores + gx(t+1) prefetch
    hs[((size_t)bb0 * TC + t) * HCAT + hcol] = hb0;
    hs[((size_t)bb1 * TC + t) * HCAT + hcol] = hb1;
    if (t + 1 < TC) {
#pragma unroll
      for (int q = 0; q < 4; ++q) {
        gxv0[q] = bf2f(gx[((size_t)bb0 * TC + t + 1) * G4 + (size_t)q * HL + u0 + u]);
        gxv1[q] = bf2f(gx[((size_t)bb1 * TC + t + 1) * G4 + (size_t)q * HL + u0 + u]);
      }
    }
  }
  cbuf[(size_t)bb0 * HCAT + hcol] = c0;
  cbuf[(size_t)bb1 * HCAT + hcol] = c1;
}

__global__ __launch_bounds__(256, 1) void k_lstm(
    const float* __restrict__ Whh0, const float* __restrict__ Whh1,
    const float* __restrict__ Whh2,
    const ushort_t* __restrict__ gx0, const ushort_t* __restrict__ gx1,
    const ushort_t* __restrict__ gx2,
    unsigned* __restrict__ hb2, float* __restrict__ cbuf,
    ushort_t* __restrict__ hs,
    unsigned* __restrict__ flags,   // [8 g][3 L][16 consumers][64 words]
    int t0, int TC)
{
  __shared__ ushort_t htile[16 * 520];
  __shared__ float gbuf[4][16][34];
  const int g    = blockIdx.x & 7;
  const int rank = blockIdx.x >> 3;        // 0..31
  if (rank < 16) {
    lstm_body<512>(Whh0, gx0, hb2, cbuf, hs, htile, gbuf,
                   flags + ((size_t)(g * 3 + 0) * 16) * 64, rank, 16,
                   g, rank * 32, 0, t0, TC);
  } else if (rank < 24) {
    lstm_body<256>(Whh1, gx1, hb2, cbuf, hs, htile, gbuf,
                   flags + ((size_t)(g * 3 + 1) * 16) * 64, rank - 16, 8,
                   g, (rank - 16) * 32, 512, t0, TC);
  } else {
    lstm_body<256>(Whh2, gx2, hb2, cbuf, hs, htile, gbuf,
                   flags + ((size_t)(g * 3 + 2) * 16) * 64, rank - 24, 8,
                   g, (rank - 24) * 32, 768, t0, TC);
  }
}

// fallback if workspace is too small: distinctive sentinel
__global__ void k_fill(float* __restrict__ out, int n, float v) {
  int i = blockIdx.x * 256 + threadIdx.x;
  if (i < n) out[i] = v;
}

extern "C" void kernel_launch(void* const* d_in, const int* in_sizes, int n_in,
                              void* d_out, int out_size, void* d_ws, size_t ws_size,
                              hipStream_t stream) {
  (void)in_sizes; (void)n_in;
  const float* x0  = (const float*)d_in[0];
  const float* x1  = (const float*)d_in[1];
  const float* x2  = (const float*)d_in[2];
  const float* Wih0 = (const float*)d_in[3];
  const float* Whh0 = (const float*)d_in[4];
  const float* bih0 = (const float*)d_in[5];
  const float* bhh0 = (const float*)d_in[6];
  const float* Wih1 = (const float*)d_in[7];
  const float* Whh1 = (const float*)d_in[8];
  const float* bih1 = (const float*)d_in[9];
  const float* bhh1 = (const float*)d_in[10];
  const float* Wih2 = (const float*)d_in[11];
  const float* Whh2 = (const float*)d_in[12];
  const float* bih2 = (const float*)d_in[13];
  const float* bhh2 = (const float*)d_in[14];
  const float* W1 = (const float*)d_in[15];
  const float* b1 = (const float*)d_in[16];
  const float* W2 = (const float*)d_in[17];
  const float* b2 = (const float*)d_in[18];
  float* out = (float*)d_out;

  const size_t szFlags = (size_t)8 * 3 * 16 * 64 * sizeof(unsigned);  // 768KB
  const size_t szHbuf  = (size_t)2 * NB * HCAT * 4;   // u32 epoch|bf16, dbuf
  const size_t szCbuf  = (size_t)NB * HCAT * 4;
  const size_t szWb0   = (size_t)2048 * KP0 * 2;
  const size_t szWb1   = (size_t)1024 * KP1 * 2;
  const size_t szWb2   = (size_t)1024 * KP2 * 2;
  const size_t szW1b   = (size_t)256 * 1024 * 2;

  const int cands[6] = {256, 128, 64, 32, 16, 8};
  int TC = 0;
  for (int ci = 0; ci < 6; ++ci) {
    int tc = cands[ci];
    size_t rows = (size_t)NB * tc;
    size_t o = 0;
    auto al = [&](size_t bytes) { o += (bytes + 255) & ~(size_t)255; };
    al(szFlags); al(szHbuf); al(szCbuf);
    al(szWb0); al(szWb1); al(szWb2); al(szW1b);
    al(rows * HCAT * 2);                // hs chunk
    al(rows * 256 * 4);                 // z chunk
    al(rows * 2048 * 2);                // gx0 chunk
    al(rows * 1024 * 2);                // gx1 chunk
    al(rows * 1024 * 2);                // gx2 chunk
    al(rows * KP0 * 2);                 // xb0
    al(rows * KP1 * 2);                 // xb1
    al(rows * KP2 * 2);                 // xb2
    if (o <= ws_size) { TC = tc; break; }
  }
  if (TC == 0) {
    k_fill<<<dim3((out_size + 255) / 256), dim3(256), 0, stream>>>(out, out_size, -8888.f);
    return;
  }
  const int tcShift = __builtin_ctz(TC);
  const size_t rows = (size_t)NB * TC;

  char* ws = (char*)d_ws;
  size_t off = 0;
  auto alloc = [&](size_t bytes) -> void* {
    void* p = ws + off;
    off += (bytes + 255) & ~(size_t)255;
    return p;
  };
  unsigned* flags = (unsigned*)alloc(szFlags);
  unsigned* hb2  = (unsigned*)alloc(szHbuf);
  float* cbuf    = (float*)alloc(szCbuf);
  size_t staticEnd = off;
  ushort_t* wb0  = (ushort_t*)alloc(szWb0);
  ushort_t* wb1  = (ushort_t*)alloc(szWb1);
  ushort_t* wb2  = (ushort_t*)alloc(szWb2);
  ushort_t* w1b  = (ushort_t*)alloc(szW1b);
  ushort_t* hs   = (ushort_t*)alloc(rows * HCAT * 2);
  float* z       = (float*)alloc(rows * 256 * 4);
  ushort_t* gx0  = (ushort_t*)alloc(rows * 2048 * 2);
  ushort_t* gx1  = (ushort_t*)alloc(rows * 1024 * 2);
  ushort_t* gx2  = (ushort_t*)alloc(rows * 1024 * 2);
  ushort_t* xb0  = (ushort_t*)alloc(rows * KP0 * 2);
  ushort_t* xb1  = (ushort_t*)alloc(rows * KP1 * 2);
  ushort_t* xb2  = (ushort_t*)alloc(rows * KP2 * 2);

  hipMemsetAsync(ws, 0, staticEnd, stream);   // flags=0, epoch 0 == h(0)=0, c(0)=0

  dim3 blk(256);
  k_cvt_w<<<dim3((2048 * KP0 + 255) / 256), blk, 0, stream>>>(Wih0, wb0, 2048, 300, KP0);
  k_cvt_w<<<dim3((1024 * KP1 + 255) / 256), blk, 0, stream>>>(Wih1, wb1, 1024, 74, KP1);
  k_cvt_w<<<dim3((1024 * KP2 + 255) / 256), blk, 0, stream>>>(Wih2, wb2, 1024, 35, KP2);
  k_cvt_w<<<dim3((256 * 1024 + 255) / 256), blk, 0, stream>>>(W1, w1b, 256, 1024, 1024);

  const int rb = (int)(rows / 64);   // row-blocks per chunk
  for (int t0 = 0; t0 < NT; t0 += TC) {
    int tot0 = (int)(rows * KP0), tot1 = (int)(rows * KP1), tot2 = (int)(rows * KP2);
    k_cvt_x<<<dim3((tot0 + 255) / 256), blk, 0, stream>>>(x0, xb0, 300, KP0, t0, tcShift, tot0);
    k_cvt_x<<<dim3((tot1 + 255) / 256), blk, 0, stream>>>(x1, xb1, 74, KP1, t0, tcShift, tot1);
    k_cvt_x<<<dim3((tot2 + 255) / 256), blk, 0, stream>>>(x2, xb2, 35, KP2, t0, tcShift, tot2);

    k_gemm<<<dim3(rb, 2048 / 64), blk, 0, stream>>>(xb0, wb0, KP0, bih0, bhh0, gx0, nullptr, 2048, 0);
    k_gemm<<<dim3(rb, 1024 / 64), blk, 0, stream>>>(xb1, wb1, KP1, bih1, bhh1, gx1, nullptr, 1024, 0);
    k_gemm<<<dim3(rb, 1024 / 64), blk, 0, stream>>>(xb2, wb2, KP2, bih2, bhh2, gx2, nullptr, 1024, 0);

    k_lstm<<<dim3(256), blk, 0, stream>>>(Whh0, Whh1, Whh2,
                                          gx0, gx1, gx2,
                                          hb2, cbuf, hs, flags, t0, TC);

    k_gemm<<<dim3(rb, 256 / 64), blk, 0, stream>>>(hs, w1b, 1024, b1, nullptr, nullptr, z, 256, 1);
    k_fc2<<<dim3((int)(rows / 4)), blk, 0, stream>>>(z, W2, b2, out, t0, tcShift);
  }
}

// Round 8
// 909.652 us; speedup vs baseline: 1.2202x; 1.2115x over previous
//
#include <hip/hip_runtime.h>
#include <hip/hip_bf16.h>
#include <math.h>

typedef __hip_bfloat16 bf16;
typedef unsigned short ushort_t;
typedef unsigned long long ull_t;
typedef __attribute__((ext_vector_type(8))) short short8;
typedef __attribute__((ext_vector_type(4))) float f32x4;

constexpr int NB = 128;      // batch
constexpr int NT = 256;      // time
constexpr int HCAT = 1024;   // 512+256+256
// padded K for bf16 GEMM operands (multiples of 64)
constexpr int KP0 = 320;     // 300
constexpr int KP1 = 128;     // 74
constexpr int KP2 = 64;      // 35

__device__ inline float bf2f(ushort_t u) {
  union { unsigned i; float f; } x; x.i = (unsigned)u << 16; return x.f;
}
__device__ inline ushort_t f2bf(float f) {
  bf16 b = __float2bfloat16(f);
  return *reinterpret_cast<ushort_t*>(&b);
}
// fast sigmoid/tanh via v_exp + v_rcp; saturate correctly at +-inf, no NaN.
__device__ inline float fsig(float x) {
  return __builtin_amdgcn_rcpf(1.f + __expf(-x));
}
__device__ inline float ftanh(float x) {
  return 2.f * __builtin_amdgcn_rcpf(1.f + __expf(-2.f * x)) - 1.f;
}

// ---------------------------------------------------------------------------
// weight convert: fp32 [R][K] -> bf16 [R][KP], zero-padded
// ---------------------------------------------------------------------------
__global__ __launch_bounds__(256) void k_cvt_w(
    const float* __restrict__ in, ushort_t* __restrict__ out, int R, int K, int KP)
{
  int i = blockIdx.x * 256 + threadIdx.x;
  if (i >= R * KP) return;
  int r = i / KP, k = i - r * KP;
  out[i] = (k < K) ? f2bf(in[(size_t)r * K + k]) : (ushort_t)0;
}

// ---------------------------------------------------------------------------
// x convert: fp32 x[B][NT][d] -> bf16 [rows][KP] (row = b*TC+tl), zero-padded
// ---------------------------------------------------------------------------
__global__ __launch_bounds__(256) void k_cvt_x(
    const float* __restrict__ x, ushort_t* __restrict__ out,
    int d, int KP, int t0, int tcShift, int total)
{
  int i = blockIdx.x * 256 + threadIdx.x;
  if (i >= total) return;
  int row = i / KP, k = i - row * KP;
  int b = row >> tcShift, tl = row & ((1 << tcShift) - 1);
  out[i] = (k < d) ? f2bf(x[((size_t)b * NT + t0 + tl) * d + k]) : (ushort_t)0;
}

// ---------------------------------------------------------------------------
// Generic bf16 B^T GEMM (R9-proven): 64x64 tile, BK=64, dbuf LDS, 1 barrier
// per chunk. mode 0: bf16 out + bias0+bias1 (gx). mode 1: fp32 relu (fc1).
// Used for the small-K GEMMs (gx1 K=128, gx2 K=64) where prologue cost
// dominates and a bigger tile loses.
// ---------------------------------------------------------------------------
__global__ __launch_bounds__(256) void k_gemm(
    const ushort_t* __restrict__ A, const ushort_t* __restrict__ B, int KP,
    const float* __restrict__ bias0, const float* __restrict__ bias1,
    ushort_t* __restrict__ outb, float* __restrict__ outf, int ldc, int mode)
{
  __shared__ ushort_t As[2][64][72];
  __shared__ ushort_t Bs[2][64][72];
  const int row0 = blockIdx.x * 64;
  const int col0 = blockIdx.y * 64;
  const int tid  = threadIdx.x;
  const int lane = tid & 63;
  const int w    = tid >> 6;
  const int n    = lane & 15;
  const int quad = lane >> 4;
  const int sr = tid >> 2;           // staging row 0..63
  const int sc = (tid & 3) * 16;     // staging col (elems)

  const ushort_t* arow = A + (size_t)(row0 + sr) * KP + sc;
  const ushort_t* brow = B + (size_t)(col0 + sr) * KP + sc;

  short8 ra0 = *reinterpret_cast<const short8*>(arow);
  short8 ra1 = *reinterpret_cast<const short8*>(arow + 8);
  short8 rb0 = *reinterpret_cast<const short8*>(brow);
  short8 rb1 = *reinterpret_cast<const short8*>(brow + 8);
  *reinterpret_cast<short8*>(&As[0][sr][sc])     = ra0;
  *reinterpret_cast<short8*>(&As[0][sr][sc + 8]) = ra1;
  *reinterpret_cast<short8*>(&Bs[0][sr][sc])     = rb0;
  *reinterpret_cast<short8*>(&Bs[0][sr][sc + 8]) = rb1;

  f32x4 acc[4] = {{0,0,0,0},{0,0,0,0},{0,0,0,0},{0,0,0,0}};
  const int nch = KP >> 6;
  for (int ch = 0; ch < nch; ++ch) {
    __syncthreads();
    const int cur = ch & 1;
    if (ch + 1 < nch) {
      const ushort_t* an = arow + (ch + 1) * 64;
      const ushort_t* bn = brow + (ch + 1) * 64;
      ra0 = *reinterpret_cast<const short8*>(an);
      ra1 = *reinterpret_cast<const short8*>(an + 8);
      rb0 = *reinterpret_cast<const short8*>(bn);
      rb1 = *reinterpret_cast<const short8*>(bn + 8);
    }
#pragma unroll
    for (int kc = 0; kc < 2; ++kc) {
      short8 bfr = *reinterpret_cast<const short8*>(&Bs[cur][w * 16 + n][quad * 8 + kc * 32]);
#pragma unroll
      for (int mt = 0; mt < 4; ++mt) {
        short8 afr = *reinterpret_cast<const short8*>(&As[cur][mt * 16 + n][quad * 8 + kc * 32]);
        acc[mt] = __builtin_amdgcn_mfma_f32_16x16x32_bf16(afr, bfr, acc[mt], 0, 0, 0);
      }
    }
    if (ch + 1 < nch) {
      const int nxt = 1 - cur;
      *reinterpret_cast<short8*>(&As[nxt][sr][sc])     = ra0;
      *reinterpret_cast<short8*>(&As[nxt][sr][sc + 8]) = ra1;
      *reinterpret_cast<short8*>(&Bs[nxt][sr][sc])     = rb0;
      *reinterpret_cast<short8*>(&Bs[nxt][sr][sc + 8]) = rb1;
    }
  }

  const int col = col0 + w * 16 + n;
  if (mode == 0) {
    const float bsum = bias0[col] + bias1[col];
#pragma unroll
    for (int mt = 0; mt < 4; ++mt)
#pragma unroll
      for (int r = 0; r < 4; ++r) {
        int row = row0 + mt * 16 + quad * 4 + r;
        outb[(size_t)row * ldc + col] = f2bf(acc[mt][r] + bsum);
      }
  } else {
    const float bsum = bias0[col];
#pragma unroll
    for (int mt = 0; mt < 4; ++mt)
#pragma unroll
      for (int r = 0; r < 4; ++r) {
        int row = row0 + mt * 16 + quad * 4 + r;
        outf[(size_t)row * ldc + col] = fmaxf(acc[mt][r] + bsum, 0.f);
      }
  }
}

// ---------------------------------------------------------------------------
// 128x128-tile bf16 B^T GEMM (R2 harness-verified, ladder step-2 structure):
// BK=64, reg-prefetch + dbuf LDS, 1 barrier/chunk; 4 waves each own a 64x64
// quadrant (4x4 frags). Used ONLY where K is large enough to amortize the
// bigger prologue: gx0 (K=320) and fc1 (K=1024).
// ---------------------------------------------------------------------------
__global__ __launch_bounds__(256) void k_gemm128(
    const ushort_t* __restrict__ A, const ushort_t* __restrict__ B, int KP,
    const float* __restrict__ bias0, const float* __restrict__ bias1,
    ushort_t* __restrict__ outb, float* __restrict__ outf, int ldc, int mode)
{
  __shared__ ushort_t As[2][128][72];
  __shared__ ushort_t Bs[2][128][72];
  const int row0 = blockIdx.x * 128;
  const int col0 = blockIdx.y * 128;
  const int tid  = threadIdx.x;
  const int lane = tid & 63;
  const int w    = tid >> 6;
  const int wr   = w >> 1;             // wave quadrant row
  const int wc   = w & 1;              // wave quadrant col
  const int n    = lane & 15;
  const int quad = lane >> 4;
  const int sr = tid >> 1;             // staging row 0..127
  const int sc = (tid & 1) * 32;       // staging col (elems)

  const ushort_t* arow = A + (size_t)(row0 + sr) * KP + sc;
  const ushort_t* brow = B + (size_t)(col0 + sr) * KP + sc;

  short8 ra[4], rb[4];
#pragma unroll
  for (int j = 0; j < 4; ++j) {
    ra[j] = *reinterpret_cast<const short8*>(arow + j * 8);
    rb[j] = *reinterpret_cast<const short8*>(brow + j * 8);
  }
#pragma unroll
  for (int j = 0; j < 4; ++j) {
    *reinterpret_cast<short8*>(&As[0][sr][sc + j * 8]) = ra[j];
    *reinterpret_cast<short8*>(&Bs[0][sr][sc + j * 8]) = rb[j];
  }

  f32x4 acc[4][4] = {};
  const int nch = KP >> 6;
  for (int ch = 0; ch < nch; ++ch) {
    __syncthreads();
    const int cur = ch & 1;
    if (ch + 1 < nch) {
      const ushort_t* an = arow + (ch + 1) * 64;
      const ushort_t* bn = brow + (ch + 1) * 64;
#pragma unroll
      for (int j = 0; j < 4; ++j) {
        ra[j] = *reinterpret_cast<const short8*>(an + j * 8);
        rb[j] = *reinterpret_cast<const short8*>(bn + j * 8);
      }
    }
#pragma unroll
    for (int kc = 0; kc < 2; ++kc) {
      short8 bfr[4];
#pragma unroll
      for (int nt = 0; nt < 4; ++nt)
        bfr[nt] = *reinterpret_cast<const short8*>(
            &Bs[cur][wc * 64 + nt * 16 + n][quad * 8 + kc * 32]);
#pragma unroll
      for (int mt = 0; mt < 4; ++mt) {
        short8 afr = *reinterpret_cast<const short8*>(
            &As[cur][wr * 64 + mt * 16 + n][quad * 8 + kc * 32]);
#pragma unroll
        for (int nt = 0; nt < 4; ++nt)
          acc[mt][nt] = __builtin_amdgcn_mfma_f32_16x16x32_bf16(afr, bfr[nt], acc[mt][nt], 0, 0, 0);
      }
    }
    if (ch + 1 < nch) {
      const int nxt = 1 - cur;
#pragma unroll
      for (int j = 0; j < 4; ++j) {
        *reinterpret_cast<short8*>(&As[nxt][sr][sc + j * 8]) = ra[j];
        *reinterpret_cast<short8*>(&Bs[nxt][sr][sc + j * 8]) = rb[j];
      }
    }
  }

#pragma unroll
  for (int nt = 0; nt < 4; ++nt) {
    const int col = col0 + wc * 64 + nt * 16 + n;
    if (mode == 0) {
      const float bsum = bias0[col] + bias1[col];
#pragma unroll
      for (int mt = 0; mt < 4; ++mt)
#pragma unroll
        for (int r = 0; r < 4; ++r) {
          int row = row0 + wr * 64 + mt * 16 + quad * 4 + r;
          outb[(size_t)row * ldc + col] = f2bf(acc[mt][nt][r] + bsum);
        }
    } else {
      const float bsum = bias0[col];
#pragma unroll
      for (int mt = 0; mt < 4; ++mt)
#pragma unroll
        for (int r = 0; r < 4; ++r) {
          int row = row0 + wr * 64 + mt * 16 + quad * 4 + r;
          outf[(size_t)row * ldc + col] = fmaxf(acc[mt][nt][r] + bsum, 0.f);
        }
    }
  }
}

// ---------------------------------------------------------------------------
// fc2 + log_softmax: one wave per chunk row; map chunk row -> global (b,t)
// ---------------------------------------------------------------------------
__global__ __launch_bounds__(256) void k_fc2(
    const float* __restrict__ Z, const float* __restrict__ W2,
    const float* __restrict__ b2, float* __restrict__ out, int t0, int tcShift)
{
  const int wave = threadIdx.x >> 6;
  const int lane = threadIdx.x & 63;
  const int bt = blockIdx.x * 4 + wave;
  const float* z = Z + (size_t)bt * 256;
  float zv[4];
#pragma unroll
  for (int j = 0; j < 4; ++j) zv[j] = z[lane + 64 * j];
  float lg[7];
#pragma unroll
  for (int o = 0; o < 7; ++o) {
    float a = 0.f;
#pragma unroll
    for (int j = 0; j < 4; ++j) a += zv[j] * W2[o * 256 + lane + 64 * j];
#pragma unroll
    for (int off = 32; off > 0; off >>= 1) a += __shfl_down(a, off, 64);
    lg[o] = a;   // valid on lane 0
  }
  if (lane == 0) {
    const int b = bt >> tcShift;
    const int tl = bt & ((1 << tcShift) - 1);
    float* op = out + ((size_t)b * NT + t0 + tl) * 7;
    float lo[7];
    float m = -1e30f;
#pragma unroll
    for (int o = 0; o < 7; ++o) { lo[o] = lg[o] + b2[o]; m = fmaxf(m, lo[o]); }
    float s = 0.f;
#pragma unroll
    for (int o = 0; o < 7; ++o) s += expf(lo[o] - m);
    float lse = m + logf(s);
#pragma unroll
    for (int o = 0; o < 7; ++o) op[o] = lo[o] - lse;
  }
}

// ---------------------------------------------------------------------------
// Recurrent kernel R11 — restored VERBATIM (best measured: 284.8us/dispatch).
// Epoch-packed h words ((epoch<<16)|bf16): data is its own flag; 2-buffer by
// step parity; relaxed agent-scope atomics; 2 barriers/step. DO NOT touch the
// poll/publish/epilogue ordering: the epilogue's gx loads+bf2f waits act as a
// calibrated backoff so the first sweep usually passes (R12/R14/R15/R16 all
// perturbed this window and regressed 17-53%).
// ---------------------------------------------------------------------------
template<int HL>
__device__ void lstm_body(const float* __restrict__ Whh,
                          const ushort_t* __restrict__ gx,   // bf16 bits, [NB][TC][4*HL]
                          unsigned* __restrict__ hb2,        // u32 [2][NB][HCAT] = epoch|bf16
                          float* __restrict__ cbuf,          // fp32 [NB][HCAT]
                          ushort_t* __restrict__ hs,         // bf16 [NB][TC][HCAT]
                          ushort_t* htile,                   // LDS [16][HL+8]
                          float (*gbuf)[16][34],             // LDS gate tiles
                          int g, int u0, int hoff, int t0, int TC)
{
  constexpr int KC  = HL / 32;
  constexpr int LHP = HL + 8;          // padded LDS row, bf16 units
  constexpr int NGR = HL / 32;         // 8-byte source granules per thread
  const int tid  = threadIdx.x;
  const int lane = tid & 63;
  const int wgate = tid >> 6;          // wave index == gate (i,f,g,o)
  const int n    = lane & 15;
  const int quad = lane >> 4;

  short8 wfrag[2][KC];
#pragma unroll
  for (int tau = 0; tau < 2; ++tau) {
    const float* wrow = Whh + ((size_t)wgate * HL + u0 + 16 * tau + n) * HL + quad * 8;
#pragma unroll
    for (int kc = 0; kc < KC; ++kc) {
      short8 f;
#pragma unroll
      for (int j = 0; j < 8; ++j) f[j] = (short)f2bf(wrow[kc * 32 + j]);
      wfrag[tau][kc] = f;
    }
  }

  const int u  = tid & 31;
  const int bh = tid >> 5;             // 0..7
  const int bb0 = g * 16 + bh;
  const int bb1 = bb0 + 8;
  const int hcol = hoff + u0 + u;
  float c0 = cbuf[(size_t)bb0 * HCAT + hcol];
  float c1 = cbuf[(size_t)bb1 * HCAT + hcol];

  const int srow = wgate * 4 + (lane >> 4);   // 0..15
  const int scol = lane & 15;
  unsigned* htile32 = reinterpret_cast<unsigned*>(htile);

  const size_t G4 = (size_t)(4 * HL);
  float gxv0[4], gxv1[4];
#pragma unroll
  for (int q = 0; q < 4; ++q) {
    gxv0[q] = bf2f(gx[((size_t)bb0 * TC) * G4 + (size_t)q * HL + u0 + u]);
    gxv1[q] = bf2f(gx[((size_t)bb1 * TC) * G4 + (size_t)q * HL + u0 + u]);
  }

  const ull_t EPM = 0xFFFF0000FFFF0000ull;

  for (int t = 0; t < TC; ++t) {
    const unsigned ep = (unsigned)(t0 + t);
    const ull_t want = ((ull_t)ep << 16) | ((ull_t)ep << 48);
    const ull_t* src64 = reinterpret_cast<const ull_t*>(
        hb2 + ((size_t)(ep & 1) * NB + g * 16 + srow) * HCAT + hoff);

    // per-thread poll: loads return payload+epoch together; a sweep issues all
    // NGR loads back-to-back (waits batched), so one sweep costs ~1 LLC latency
    ull_t vv[NGR];
    while (true) {
#pragma unroll
      for (int i = 0; i < NGR; ++i)
        vv[i] = __hip_atomic_load(src64 + scol + i * 16,
                                  __ATOMIC_RELAXED, __HIP_MEMORY_SCOPE_AGENT);
      ull_t bad = 0;
#pragma unroll
      for (int i = 0; i < NGR; ++i) bad |= (vv[i] ^ want) & EPM;
      if (bad == 0) break;
      __builtin_amdgcn_s_sleep(1);
    }
#pragma unroll
    for (int i = 0; i < NGR; ++i)
      htile32[srow * (LHP / 2) + scol + i * 16] =
          (unsigned)(vv[i] & 0xffffu) | ((unsigned)(vv[i] >> 16) & 0xffff0000u);
    __syncthreads();   // htile complete (also orders prev-step gbuf reads vs writes)

    f32x4 acc0 = {0.f, 0.f, 0.f, 0.f};
    f32x4 acc1 = {0.f, 0.f, 0.f, 0.f};
#pragma unroll
    for (int kc = 0; kc < KC; ++kc) {
      short8 a = *reinterpret_cast<const short8*>(htile + n * LHP + quad * 8 + kc * 32);
      acc0 = __builtin_amdgcn_mfma_f32_16x16x32_bf16(a, wfrag[0][kc], acc0, 0, 0, 0);
      acc1 = __builtin_amdgcn_mfma_f32_16x16x32_bf16(a, wfrag[1][kc], acc1, 0, 0, 0);
    }
#pragma unroll
    for (int r = 0; r < 4; ++r) {
      gbuf[wgate][quad * 4 + r][n]      = acc0[r];
      gbuf[wgate][quad * 4 + r][16 + n] = acc1[r];
    }
    __syncthreads();   // gbuf ready (also ensures all htile reads done)

    float pi0 = gbuf[0][bh][u] + gxv0[0];
    float pf0 = gbuf[1][bh][u] + gxv0[1];
    float pg0 = gbuf[2][bh][u] + gxv0[2];
    float po0 = gbuf[3][bh][u] + gxv0[3];
    float pi1 = gbuf[0][bh + 8][u] + gxv1[0];
    float pf1 = gbuf[1][bh + 8][u] + gxv1[1];
    float pg1 = gbuf[2][bh + 8][u] + gxv1[2];
    float po1 = gbuf[3][bh + 8][u] + gxv1[3];

    float si0 = fsig(pi0), sf0 = fsig(pf0), so0 = fsig(po0);
    float tg0 = ftanh(pg0);
    c0 = sf0 * c0 + si0 * tg0;
    float h0 = so0 * ftanh(c0);
    float si1 = fsig(pi1), sf1 = fsig(pf1), so1 = fsig(po1);
    float tg1 = ftanh(pg1);
    c1 = sf1 * c1 + si1 * tg1;
    float h1 = so1 * ftanh(c1);

    // publish h(t+1): payload and validity in one atomic 4B word — no fence,
    // no drain, no flag. Issued immediately; everything after is off-path.
    const ushort_t hb0 = f2bf(h0), hb1 = f2bf(h1);
    const unsigned ep1 = (ep + 1) << 16;
    unsigned* nxt = hb2 + (size_t)((ep + 1) & 1) * NB * HCAT;
    __hip_atomic_store(nxt + (size_t)bb0 * HCAT + hcol, ep1 | (unsigned)hb0,
                       __ATOMIC_RELAXED, __HIP_MEMORY_SCOPE_AGENT);
    __hip_atomic_store(nxt + (size_t)bb1 * HCAT + hcol, ep1 | (unsigned)hb1,
                       __ATOMIC_RELAXED, __HIP_MEMORY_SCOPE_AGENT);

    // off-critical-path: hs stores + gx(t+1) prefetch
    hs[((size_t)bb0 * TC + t) * HCAT + hcol] = hb0;
    hs[((size_t)bb1 * TC + t) * HCAT + hcol] = hb1;
    if (t + 1 < TC) {
#pragma unroll
      for (int q = 0; q < 4; ++q) {
        gxv0[q] = bf2f(gx[((size_t)bb0 * TC + t + 1) * G4 + (size_t)q * HL + u0 + u]);
        gxv1[q] = bf2f(gx[((size_t)bb1 * TC + t + 1) * G4 + (size_t)q * HL + u0 + u]);
      }
    }
  }
  cbuf[(size_t)bb0 * HCAT + hcol] = c0;
  cbuf[(size_t)bb1 * HCAT + hcol] = c1;
}

__global__ __launch_bounds__(256, 1) void k_lstm(
    const float* __restrict__ Whh0, const float* __restrict__ Whh1,
    const float* __restrict__ Whh2,
    const ushort_t* __restrict__ gx0, const ushort_t* __restrict__ gx1,
    const ushort_t* __restrict__ gx2,
    unsigned* __restrict__ hb2, float* __restrict__ cbuf,
    ushort_t* __restrict__ hs,
    int t0, int TC)
{
  __shared__ ushort_t htile[16 * 520];
  __shared__ float gbuf[4][16][34];
  const int g    = blockIdx.x & 7;
  const int rank = blockIdx.x >> 3;        // 0..31
  if (rank < 16) {
    lstm_body<512>(Whh0, gx0, hb2, cbuf, hs, htile, gbuf,
                   g, rank * 32, 0, t0, TC);
  } else if (rank < 24) {
    lstm_body<256>(Whh1, gx1, hb2, cbuf, hs, htile, gbuf,
                   g, (rank - 16) * 32, 512, t0, TC);
  } else {
    lstm_body<256>(Whh2, gx2, hb2, cbuf, hs, htile, gbuf,
                   g, (rank - 24) * 32, 768, t0, TC);
  }
}

// fallback if workspace is too small: distinctive sentinel
__global__ void k_fill(float* __restrict__ out, int n, float v) {
  int i = blockIdx.x * 256 + threadIdx.x;
  if (i < n) out[i] = v;
}

extern "C" void kernel_launch(void* const* d_in, const int* in_sizes, int n_in,
                              void* d_out, int out_size, void* d_ws, size_t ws_size,
                              hipStream_t stream) {
  (void)in_sizes; (void)n_in;
  const float* x0  = (const float*)d_in[0];
  const float* x1  = (const float*)d_in[1];
  const float* x2  = (const float*)d_in[2];
  const float* Wih0 = (const float*)d_in[3];
  const float* Whh0 = (const float*)d_in[4];
  const float* bih0 = (const float*)d_in[5];
  const float* bhh0 = (const float*)d_in[6];
  const float* Wih1 = (const float*)d_in[7];
  const float* Whh1 = (const float*)d_in[8];
  const float* bih1 = (const float*)d_in[9];
  const float* bhh1 = (const float*)d_in[10];
  const float* Wih2 = (const float*)d_in[11];
  const float* Whh2 = (const float*)d_in[12];
  const float* bih2 = (const float*)d_in[13];
  const float* bhh2 = (const float*)d_in[14];
  const float* W1 = (const float*)d_in[15];
  const float* b1 = (const float*)d_in[16];
  const float* W2 = (const float*)d_in[17];
  const float* b2 = (const float*)d_in[18];
  float* out = (float*)d_out;

  const size_t szHbuf  = (size_t)2 * NB * HCAT * 4;   // u32 epoch|bf16, dbuf
  const size_t szCbuf  = (size_t)NB * HCAT * 4;
  const size_t szWb0   = (size_t)2048 * KP0 * 2;
  const size_t szWb1   = (size_t)1024 * KP1 * 2;
  const size_t szWb2   = (size_t)1024 * KP2 * 2;
  const size_t szW1b   = (size_t)256 * 1024 * 2;

  const int cands[6] = {256, 128, 64, 32, 16, 8};
  int TC = 0;
  for (int ci = 0; ci < 6; ++ci) {
    int tc = cands[ci];
    size_t rows = (size_t)NB * tc;
    size_t o = 0;
    auto al = [&](size_t bytes) { o += (bytes + 255) & ~(size_t)255; };
    al(szHbuf); al(szCbuf);
    al(szWb0); al(szWb1); al(szWb2); al(szW1b);
    al(rows * HCAT * 2);                // hs chunk
    al(rows * 256 * 4);                 // z chunk
    al(rows * 2048 * 2);                // gx0 chunk
    al(rows * 1024 * 2);                // gx1 chunk
    al(rows * 1024 * 2);                // gx2 chunk
    al(rows * KP0 * 2);                 // xb0
    al(rows * KP1 * 2);                 // xb1
    al(rows * KP2 * 2);                 // xb2
    if (o <= ws_size) { TC = tc; break; }
  }
  if (TC == 0) {
    k_fill<<<dim3((out_size + 255) / 256), dim3(256), 0, stream>>>(out, out_size, -8888.f);
    return;
  }
  const int tcShift = __builtin_ctz(TC);
  const size_t rows = (size_t)NB * TC;

  char* ws = (char*)d_ws;
  size_t off = 0;
  auto alloc = [&](size_t bytes) -> void* {
    void* p = ws + off;
    off += (bytes + 255) & ~(size_t)255;
    return p;
  };
  unsigned* hb2  = (unsigned*)alloc(szHbuf);
  float* cbuf    = (float*)alloc(szCbuf);
  size_t staticEnd = off;
  ushort_t* wb0  = (ushort_t*)alloc(szWb0);
  ushort_t* wb1  = (ushort_t*)alloc(szWb1);
  ushort_t* wb2  = (ushort_t*)alloc(szWb2);
  ushort_t* w1b  = (ushort_t*)alloc(szW1b);
  ushort_t* hs   = (ushort_t*)alloc(rows * HCAT * 2);
  float* z       = (float*)alloc(rows * 256 * 4);
  ushort_t* gx0  = (ushort_t*)alloc(rows * 2048 * 2);
  ushort_t* gx1  = (ushort_t*)alloc(rows * 1024 * 2);
  ushort_t* gx2  = (ushort_t*)alloc(rows * 1024 * 2);
  ushort_t* xb0  = (ushort_t*)alloc(rows * KP0 * 2);
  ushort_t* xb1  = (ushort_t*)alloc(rows * KP1 * 2);
  ushort_t* xb2  = (ushort_t*)alloc(rows * KP2 * 2);

  hipMemsetAsync(ws, 0, staticEnd, stream);   // epoch 0 == h(0) == 0, c(0) == 0

  dim3 blk(256);
  k_cvt_w<<<dim3((2048 * KP0 + 255) / 256), blk, 0, stream>>>(Wih0, wb0, 2048, 300, KP0);
  k_cvt_w<<<dim3((1024 * KP1 + 255) / 256), blk, 0, stream>>>(Wih1, wb1, 1024, 74, KP1);
  k_cvt_w<<<dim3((1024 * KP2 + 255) / 256), blk, 0, stream>>>(Wih2, wb2, 1024, 35, KP2);
  k_cvt_w<<<dim3((256 * 1024 + 255) / 256), blk, 0, stream>>>(W1, w1b, 256, 1024, 1024);

  const int rb  = (int)(rows / 64);    // 64-row blocks per chunk
  const int rbm = (int)(rows / 128);   // 128-row blocks per chunk
  for (int t0 = 0; t0 < NT; t0 += TC) {
    int tot0 = (int)(rows * KP0), tot1 = (int)(rows * KP1), tot2 = (int)(rows * KP2);
    k_cvt_x<<<dim3((tot0 + 255) / 256), blk, 0, stream>>>(x0, xb0, 300, KP0, t0, tcShift, tot0);
    k_cvt_x<<<dim3((tot1 + 255) / 256), blk, 0, stream>>>(x1, xb1, 74, KP1, t0, tcShift, tot1);
    k_cvt_x<<<dim3((tot2 + 255) / 256), blk, 0, stream>>>(x2, xb2, 35, KP2, t0, tcShift, tot2);

    // gx0: K=320 -> 128^2 tile (5 K-chunks amortize the bigger prologue)
    k_gemm128<<<dim3(rbm, 2048 / 128), blk, 0, stream>>>(xb0, wb0, KP0, bih0, bhh0, gx0, nullptr, 2048, 0);
    // gx1/gx2: K=128/64 -> keep 64^2 (prologue-dominated at 128^2)
    k_gemm<<<dim3(rb, 1024 / 64), blk, 0, stream>>>(xb1, wb1, KP1, bih1, bhh1, gx1, nullptr, 1024, 0);
    k_gemm<<<dim3(rb, 1024 / 64), blk, 0, stream>>>(xb2, wb2, KP2, bih2, bhh2, gx2, nullptr, 1024, 0);

    k_lstm<<<dim3(256), blk, 0, stream>>>(Whh0, Whh1, Whh2,
                                          gx0, gx1, gx2,
                                          hb2, cbuf, hs, t0, TC);

    // fc1: K=1024 -> 128^2 tile (16 K-chunks, N=256 = exactly 2 col-blocks)
    k_gemm128<<<dim3(rbm, 256 / 128), blk, 0, stream>>>(hs, w1b, 1024, b1, nullptr, nullptr, z, 256, 1);
    k_fc2<<<dim3((int)(rows / 4)), blk, 0, stream>>>(z, W2, b2, out, t0, tcShift);
  }
}

// Round 9
// 894.505 us; speedup vs baseline: 1.2409x; 1.0169x over previous
//
#include <hip/hip_runtime.h>
#include <hip/hip_bf16.h>
#include <math.h>

typedef __hip_bfloat16 bf16;
typedef unsigned short ushort_t;
typedef unsigned long long ull_t;
typedef __attribute__((ext_vector_type(8))) short short8;
typedef __attribute__((ext_vector_type(4))) float f32x4;

constexpr int NB = 128;      // batch
constexpr int NT = 256;      // time
constexpr int HCAT = 1024;   // 512+256+256
// padded K for bf16 GEMM operands (multiples of 64)
constexpr int KP0 = 320;     // 300
constexpr int KP1 = 128;     // 74
constexpr int KP2 = 64;      // 35

__device__ inline float bf2f(ushort_t u) {
  union { unsigned i; float f; } x; x.i = (unsigned)u << 16; return x.f;
}
__device__ inline ushort_t f2bf(float f) {
  bf16 b = __float2bfloat16(f);
  return *reinterpret_cast<ushort_t*>(&b);
}
// fast sigmoid/tanh via v_exp + v_rcp; saturate correctly at +-inf, no NaN.
__device__ inline float fsig(float x) {
  return __builtin_amdgcn_rcpf(1.f + __expf(-x));
}
__device__ inline float ftanh(float x) {
  return 2.f * __builtin_amdgcn_rcpf(1.f + __expf(-2.f * x)) - 1.f;
}

// ---------------------------------------------------------------------------
// merged weight convert (one launch): 4 fp32 [R][K] -> bf16 [R][KP] buffers
// ranges are compile-time so each division is by a constant.
// ---------------------------------------------------------------------------
__global__ __launch_bounds__(256) void k_cvt_w4(
    const float* __restrict__ w0, const float* __restrict__ w1,
    const float* __restrict__ w2, const float* __restrict__ w3,
    ushort_t* __restrict__ o0, ushort_t* __restrict__ o1,
    ushort_t* __restrict__ o2, ushort_t* __restrict__ o3)
{
  constexpr int T0 = 2048 * KP0;            // Wih0: 2048 x 300 -> 320
  constexpr int T1 = 1024 * KP1;            // Wih1: 1024 x 74  -> 128
  constexpr int T2 = 1024 * KP2;            // Wih2: 1024 x 35  -> 64
  constexpr int T3 = 256 * 1024;            // fc_W1: 256 x 1024 (no pad)
  int i = blockIdx.x * 256 + threadIdx.x;
  if (i < T0) {
    int r = i / KP0, k = i - r * KP0;
    o0[i] = (k < 300) ? f2bf(w0[(size_t)r * 300 + k]) : (ushort_t)0;
  } else if (i < T0 + T1) {
    int j = i - T0;
    int r = j / KP1, k = j - r * KP1;
    o1[j] = (k < 74) ? f2bf(w1[(size_t)r * 74 + k]) : (ushort_t)0;
  } else if (i < T0 + T1 + T2) {
    int j = i - T0 - T1;
    int r = j / KP2, k = j - r * KP2;
    o2[j] = (k < 35) ? f2bf(w2[(size_t)r * 35 + k]) : (ushort_t)0;
  } else if (i < T0 + T1 + T2 + T3) {
    int j = i - T0 - T1 - T2;
    o3[j] = f2bf(w3[j]);                    // K == KP == 1024
  }
}

// ---------------------------------------------------------------------------
// merged x convert (one launch per chunk): 3 fp32 x[B][NT][d] -> bf16
// [rows][KP] (row = b*TC+tl), zero-padded. Ranges scale with TC (runtime),
// but KP/d are compile-time per branch.
// ---------------------------------------------------------------------------
__global__ __launch_bounds__(256) void k_cvt_x3(
    const float* __restrict__ x0, const float* __restrict__ x1,
    const float* __restrict__ x2,
    ushort_t* __restrict__ o0, ushort_t* __restrict__ o1,
    ushort_t* __restrict__ o2,
    int t0, int tcShift, int rows)
{
  const int tot0 = rows * KP0;
  const int tot1 = rows * KP1;
  const int tot2 = rows * KP2;
  int i = blockIdx.x * 256 + threadIdx.x;
  if (i < tot0) {
    int row = i / KP0, k = i - row * KP0;
    int b = row >> tcShift, tl = row & ((1 << tcShift) - 1);
    o0[i] = (k < 300) ? f2bf(x0[((size_t)b * NT + t0 + tl) * 300 + k]) : (ushort_t)0;
  } else if (i < tot0 + tot1) {
    int j = i - tot0;
    int row = j / KP1, k = j - row * KP1;
    int b = row >> tcShift, tl = row & ((1 << tcShift) - 1);
    o1[j] = (k < 74) ? f2bf(x1[((size_t)b * NT + t0 + tl) * 74 + k]) : (ushort_t)0;
  } else if (i < tot0 + tot1 + tot2) {
    int j = i - tot0 - tot1;
    int row = j / KP2, k = j - row * KP2;
    int b = row >> tcShift, tl = row & ((1 << tcShift) - 1);
    o2[j] = (k < 35) ? f2bf(x2[((size_t)b * NT + t0 + tl) * 35 + k]) : (ushort_t)0;
  }
}

// ---------------------------------------------------------------------------
// Generic bf16 B^T GEMM (R9-proven): 64x64 tile, BK=64, dbuf LDS, 1 barrier
// per chunk. mode 0: bf16 out + bias0+bias1 (gx). mode 1: fp32 relu (fc1).
// Used for the small-K GEMMs (gx1 K=128, gx2 K=64) where prologue cost
// dominates and a bigger tile loses.
// ---------------------------------------------------------------------------
__global__ __launch_bounds__(256) void k_gemm(
    const ushort_t* __restrict__ A, const ushort_t* __restrict__ B, int KP,
    const float* __restrict__ bias0, const float* __restrict__ bias1,
    ushort_t* __restrict__ outb, float* __restrict__ outf, int ldc, int mode)
{
  __shared__ ushort_t As[2][64][72];
  __shared__ ushort_t Bs[2][64][72];
  const int row0 = blockIdx.x * 64;
  const int col0 = blockIdx.y * 64;
  const int tid  = threadIdx.x;
  const int lane = tid & 63;
  const int w    = tid >> 6;
  const int n    = lane & 15;
  const int quad = lane >> 4;
  const int sr = tid >> 2;           // staging row 0..63
  const int sc = (tid & 3) * 16;     // staging col (elems)

  const ushort_t* arow = A + (size_t)(row0 + sr) * KP + sc;
  const ushort_t* brow = B + (size_t)(col0 + sr) * KP + sc;

  short8 ra0 = *reinterpret_cast<const short8*>(arow);
  short8 ra1 = *reinterpret_cast<const short8*>(arow + 8);
  short8 rb0 = *reinterpret_cast<const short8*>(brow);
  short8 rb1 = *reinterpret_cast<const short8*>(brow + 8);
  *reinterpret_cast<short8*>(&As[0][sr][sc])     = ra0;
  *reinterpret_cast<short8*>(&As[0][sr][sc + 8]) = ra1;
  *reinterpret_cast<short8*>(&Bs[0][sr][sc])     = rb0;
  *reinterpret_cast<short8*>(&Bs[0][sr][sc + 8]) = rb1;

  f32x4 acc[4] = {{0,0,0,0},{0,0,0,0},{0,0,0,0},{0,0,0,0}};
  const int nch = KP >> 6;
  for (int ch = 0; ch < nch; ++ch) {
    __syncthreads();
    const int cur = ch & 1;
    if (ch + 1 < nch) {
      const ushort_t* an = arow + (ch + 1) * 64;
      const ushort_t* bn = brow + (ch + 1) * 64;
      ra0 = *reinterpret_cast<const short8*>(an);
      ra1 = *reinterpret_cast<const short8*>(an + 8);
      rb0 = *reinterpret_cast<const short8*>(bn);
      rb1 = *reinterpret_cast<const short8*>(bn + 8);
    }
#pragma unroll
    for (int kc = 0; kc < 2; ++kc) {
      short8 bfr = *reinterpret_cast<const short8*>(&Bs[cur][w * 16 + n][quad * 8 + kc * 32]);
#pragma unroll
      for (int mt = 0; mt < 4; ++mt) {
        short8 afr = *reinterpret_cast<const short8*>(&As[cur][mt * 16 + n][quad * 8 + kc * 32]);
        acc[mt] = __builtin_amdgcn_mfma_f32_16x16x32_bf16(afr, bfr, acc[mt], 0, 0, 0);
      }
    }
    if (ch + 1 < nch) {
      const int nxt = 1 - cur;
      *reinterpret_cast<short8*>(&As[nxt][sr][sc])     = ra0;
      *reinterpret_cast<short8*>(&As[nxt][sr][sc + 8]) = ra1;
      *reinterpret_cast<short8*>(&Bs[nxt][sr][sc])     = rb0;
      *reinterpret_cast<short8*>(&Bs[nxt][sr][sc + 8]) = rb1;
    }
  }

  const int col = col0 + w * 16 + n;
  if (mode == 0) {
    const float bsum = bias0[col] + bias1[col];
#pragma unroll
    for (int mt = 0; mt < 4; ++mt)
#pragma unroll
      for (int r = 0; r < 4; ++r) {
        int row = row0 + mt * 16 + quad * 4 + r;
        outb[(size_t)row * ldc + col] = f2bf(acc[mt][r] + bsum);
      }
  } else {
    const float bsum = bias0[col];
#pragma unroll
    for (int mt = 0; mt < 4; ++mt)
#pragma unroll
      for (int r = 0; r < 4; ++r) {
        int row = row0 + mt * 16 + quad * 4 + r;
        outf[(size_t)row * ldc + col] = fmaxf(acc[mt][r] + bsum, 0.f);
      }
  }
}

// ---------------------------------------------------------------------------
// 128x128-tile bf16 B^T GEMM (R2 harness-verified, ladder step-2 structure):
// BK=64, reg-prefetch + dbuf LDS, 1 barrier/chunk; 4 waves each own a 64x64
// quadrant (4x4 frags). Used ONLY where K is large enough to amortize the
// bigger prologue: gx0 (K=320) and fc1 (K=1024).  [R17: -22us vs all-64^2]
// ---------------------------------------------------------------------------
__global__ __launch_bounds__(256) void k_gemm128(
    const ushort_t* __restrict__ A, const ushort_t* __restrict__ B, int KP,
    const float* __restrict__ bias0, const float* __restrict__ bias1,
    ushort_t* __restrict__ outb, float* __restrict__ outf, int ldc, int mode)
{
  __shared__ ushort_t As[2][128][72];
  __shared__ ushort_t Bs[2][128][72];
  const int row0 = blockIdx.x * 128;
  const int col0 = blockIdx.y * 128;
  const int tid  = threadIdx.x;
  const int lane = tid & 63;
  const int w    = tid >> 6;
  const int wr   = w >> 1;             // wave quadrant row
  const int wc   = w & 1;              // wave quadrant col
  const int n    = lane & 15;
  const int quad = lane >> 4;
  const int sr = tid >> 1;             // staging row 0..127
  const int sc = (tid & 1) * 32;       // staging col (elems)

  const ushort_t* arow = A + (size_t)(row0 + sr) * KP + sc;
  const ushort_t* brow = B + (size_t)(col0 + sr) * KP + sc;

  short8 ra[4], rb[4];
#pragma unroll
  for (int j = 0; j < 4; ++j) {
    ra[j] = *reinterpret_cast<const short8*>(arow + j * 8);
    rb[j] = *reinterpret_cast<const short8*>(brow + j * 8);
  }
#pragma unroll
  for (int j = 0; j < 4; ++j) {
    *reinterpret_cast<short8*>(&As[0][sr][sc + j * 8]) = ra[j];
    *reinterpret_cast<short8*>(&Bs[0][sr][sc + j * 8]) = rb[j];
  }

  f32x4 acc[4][4] = {};
  const int nch = KP >> 6;
  for (int ch = 0; ch < nch; ++ch) {
    __syncthreads();
    const int cur = ch & 1;
    if (ch + 1 < nch) {
      const ushort_t* an = arow + (ch + 1) * 64;
      const ushort_t* bn = brow + (ch + 1) * 64;
#pragma unroll
      for (int j = 0; j < 4; ++j) {
        ra[j] = *reinterpret_cast<const short8*>(an + j * 8);
        rb[j] = *reinterpret_cast<const short8*>(bn + j * 8);
      }
    }
#pragma unroll
    for (int kc = 0; kc < 2; ++kc) {
      short8 bfr[4];
#pragma unroll
      for (int nt = 0; nt < 4; ++nt)
        bfr[nt] = *reinterpret_cast<const short8*>(
            &Bs[cur][wc * 64 + nt * 16 + n][quad * 8 + kc * 32]);
#pragma unroll
      for (int mt = 0; mt < 4; ++mt) {
        short8 afr = *reinterpret_cast<const short8*>(
            &As[cur][wr * 64 + mt * 16 + n][quad * 8 + kc * 32]);
#pragma unroll
        for (int nt = 0; nt < 4; ++nt)
          acc[mt][nt] = __builtin_amdgcn_mfma_f32_16x16x32_bf16(afr, bfr[nt], acc[mt][nt], 0, 0, 0);
      }
    }
    if (ch + 1 < nch) {
      const int nxt = 1 - cur;
#pragma unroll
      for (int j = 0; j < 4; ++j) {
        *reinterpret_cast<short8*>(&As[nxt][sr][sc + j * 8]) = ra[j];
        *reinterpret_cast<short8*>(&Bs[nxt][sr][sc + j * 8]) = rb[j];
      }
    }
  }

#pragma unroll
  for (int nt = 0; nt < 4; ++nt) {
    const int col = col0 + wc * 64 + nt * 16 + n;
    if (mode == 0) {
      const float bsum = bias0[col] + bias1[col];
#pragma unroll
      for (int mt = 0; mt < 4; ++mt)
#pragma unroll
        for (int r = 0; r < 4; ++r) {
          int row = row0 + wr * 64 + mt * 16 + quad * 4 + r;
          outb[(size_t)row * ldc + col] = f2bf(acc[mt][nt][r] + bsum);
        }
    } else {
      const float bsum = bias0[col];
#pragma unroll
      for (int mt = 0; mt < 4; ++mt)
#pragma unroll
        for (int r = 0; r < 4; ++r) {
          int row = row0 + wr * 64 + mt * 16 + quad * 4 + r;
          outf[(size_t)row * ldc + col] = fmaxf(acc[mt][nt][r] + bsum, 0.f);
        }
    }
  }
}

// ---------------------------------------------------------------------------
// fc2 + log_softmax: one wave per chunk row; map chunk row -> global (b,t)
// ---------------------------------------------------------------------------
__global__ __launch_bounds__(256) void k_fc2(
    const float* __restrict__ Z, const float* __restrict__ W2,
    const float* __restrict__ b2, float* __restrict__ out, int t0, int tcShift)
{
  const int wave = threadIdx.x >> 6;
  const int lane = threadIdx.x & 63;
  const int bt = blockIdx.x * 4 + wave;
  const float* z = Z + (size_t)bt * 256;
  float zv[4];
#pragma unroll
  for (int j = 0; j < 4; ++j) zv[j] = z[lane + 64 * j];
  float lg[7];
#pragma unroll
  for (int o = 0; o < 7; ++o) {
    float a = 0.f;
#pragma unroll
    for (int j = 0; j < 4; ++j) a += zv[j] * W2[o * 256 + lane + 64 * j];
#pragma unroll
    for (int off = 32; off > 0; off >>= 1) a += __shfl_down(a, off, 64);
    lg[o] = a;   // valid on lane 0
  }
  if (lane == 0) {
    const int b = bt >> tcShift;
    const int tl = bt & ((1 << tcShift) - 1);
    float* op = out + ((size_t)b * NT + t0 + tl) * 7;
    float lo[7];
    float m = -1e30f;
#pragma unroll
    for (int o = 0; o < 7; ++o) { lo[o] = lg[o] + b2[o]; m = fmaxf(m, lo[o]); }
    float s = 0.f;
#pragma unroll
    for (int o = 0; o < 7; ++o) s += expf(lo[o] - m);
    float lse = m + logf(s);
#pragma unroll
    for (int o = 0; o < 7; ++o) op[o] = lo[o] - lse;
  }
}

// ---------------------------------------------------------------------------
// Recurrent kernel R11 — VERBATIM (measured equilibrium: ~285-291us/dispatch).
// Epoch-packed h words ((epoch<<16)|bf16): data is its own flag; 2-buffer by
// step parity; relaxed agent-scope atomics; 2 barriers/step. DO NOT touch the
// poll/publish/epilogue ordering: the epilogue's gx loads+bf2f waits act as a
// calibrated backoff so the first sweep usually passes (R12/R14/R15/R16 all
// perturbed this window and regressed 17-53%).
// ---------------------------------------------------------------------------
template<int HL>
__device__ void lstm_body(const float* __restrict__ Whh,
                          const ushort_t* __restrict__ gx,   // bf16 bits, [NB][TC][4*HL]
                          unsigned* __restrict__ hb2,        // u32 [2][NB][HCAT] = epoch|bf16
                          float* __restrict__ cbuf,          // fp32 [NB][HCAT]
                          ushort_t* __restrict__ hs,         // bf16 [NB][TC][HCAT]
                          ushort_t* htile,                   // LDS [16][HL+8]
                          float (*gbuf)[16][34],             // LDS gate tiles
                          int g, int u0, int hoff, int t0, int TC)
{
  constexpr int KC  = HL / 32;
  constexpr int LHP = HL + 8;          // padded LDS row, bf16 units
  constexpr int NGR = HL / 32;         // 8-byte source granules per thread
  const int tid  = threadIdx.x;
  const int lane = tid & 63;
  const int wgate = tid >> 6;          // wave index == gate (i,f,g,o)
  const int n    = lane & 15;
  const int quad = lane >> 4;

  short8 wfrag[2][KC];
#pragma unroll
  for (int tau = 0; tau < 2; ++tau) {
    const float* wrow = Whh + ((size_t)wgate * HL + u0 + 16 * tau + n) * HL + quad * 8;
#pragma unroll
    for (int kc = 0; kc < KC; ++kc) {
      short8 f;
#pragma unroll
      for (int j = 0; j < 8; ++j) f[j] = (short)f2bf(wrow[kc * 32 + j]);
      wfrag[tau][kc] = f;
    }
  }

  const int u  = tid & 31;
  const int bh = tid >> 5;             // 0..7
  const int bb0 = g * 16 + bh;
  const int bb1 = bb0 + 8;
  const int hcol = hoff + u0 + u;
  float c0 = cbuf[(size_t)bb0 * HCAT + hcol];
  float c1 = cbuf[(size_t)bb1 * HCAT + hcol];

  const int srow = wgate * 4 + (lane >> 4);   // 0..15
  const int scol = lane & 15;
  unsigned* htile32 = reinterpret_cast<unsigned*>(htile);

  const size_t G4 = (size_t)(4 * HL);
  float gxv0[4], gxv1[4];
#pragma unroll
  for (int q = 0; q < 4; ++q) {
    gxv0[q] = bf2f(gx[((size_t)bb0 * TC) * G4 + (size_t)q * HL + u0 + u]);
    gxv1[q] = bf2f(gx[((size_t)bb1 * TC) * G4 + (size_t)q * HL + u0 + u]);
  }

  const ull_t EPM = 0xFFFF0000FFFF0000ull;

  for (int t = 0; t < TC; ++t) {
    const unsigned ep = (unsigned)(t0 + t);
    const ull_t want = ((ull_t)ep << 16) | ((ull_t)ep << 48);
    const ull_t* src64 = reinterpret_cast<const ull_t*>(
        hb2 + ((size_t)(ep & 1) * NB + g * 16 + srow) * HCAT + hoff);

    // per-thread poll: loads return payload+epoch together; a sweep issues all
    // NGR loads back-to-back (waits batched), so one sweep costs ~1 LLC latency
    ull_t vv[NGR];
    while (true) {
#pragma unroll
      for (int i = 0; i < NGR; ++i)
        vv[i] = __hip_atomic_load(src64 + scol + i * 16,
                                  __ATOMIC_RELAXED, __HIP_MEMORY_SCOPE_AGENT);
      ull_t bad = 0;
#pragma unroll
      for (int i = 0; i < NGR; ++i) bad |= (vv[i] ^ want) & EPM;
      if (bad == 0) break;
      __builtin_amdgcn_s_sleep(1);
    }
#pragma unroll
    for (int i = 0; i < NGR; ++i)
      htile32[srow * (LHP / 2) + scol + i * 16] =
          (unsigned)(vv[i] & 0xffffu) | ((unsigned)(vv[i] >> 16) & 0xffff0000u);
    __syncthreads();   // htile complete (also orders prev-step gbuf reads vs writes)

    f32x4 acc0 = {0.f, 0.f, 0.f, 0.f};
    f32x4 acc1 = {0.f, 0.f, 0.f, 0.f};
#pragma unroll
    for (int kc = 0; kc < KC; ++kc) {
      short8 a = *reinterpret_cast<const short8*>(htile + n * LHP + quad * 8 + kc * 32);
      acc0 = __builtin_amdgcn_mfma_f32_16x16x32_bf16(a, wfrag[0][kc], acc0, 0, 0, 0);
      acc1 = __builtin_amdgcn_mfma_f32_16x16x32_bf16(a, wfrag[1][kc], acc1, 0, 0, 0);
    }
#pragma unroll
    for (int r = 0; r < 4; ++r) {
      gbuf[wgate][quad * 4 + r][n]      = acc0[r];
      gbuf[wgate][quad * 4 + r][16 + n] = acc1[r];
    }
    __syncthreads();   // gbuf ready (also ensures all htile reads done)

    float pi0 = gbuf[0][bh][u] + gxv0[0];
    float pf0 = gbuf[1][bh][u] + gxv0[1];
    float pg0 = gbuf[2][bh][u] + gxv0[2];
    float po0 = gbuf[3][bh][u] + gxv0[3];
    float pi1 = gbuf[0][bh + 8][u] + gxv1[0];
    float pf1 = gbuf[1][bh + 8][u] + gxv1[1];
    float pg1 = gbuf[2][bh + 8][u] + gxv1[2];
    float po1 = gbuf[3][bh + 8][u] + gxv1[3];

    float si0 = fsig(pi0), sf0 = fsig(pf0), so0 = fsig(po0);
    float tg0 = ftanh(pg0);
    c0 = sf0 * c0 + si0 * tg0;
    float h0 = so0 * ftanh(c0);
    float si1 = fsig(pi1), sf1 = fsig(pf1), so1 = fsig(po1);
    float tg1 = ftanh(pg1);
    c1 = sf1 * c1 + si1 * tg1;
    float h1 = so1 * ftanh(c1);

    // publish h(t+1): payload and validity in one atomic 4B word — no fence,
    // no drain, no flag. Issued immediately; everything after is off-path.
    const ushort_t hb0 = f2bf(h0), hb1 = f2bf(h1);
    const unsigned ep1 = (ep + 1) << 16;
    unsigned* nxt = hb2 + (size_t)((ep + 1) & 1) * NB * HCAT;
    __hip_atomic_store(nxt + (size_t)bb0 * HCAT + hcol, ep1 | (unsigned)hb0,
                       __ATOMIC_RELAXED, __HIP_MEMORY_SCOPE_AGENT);
    __hip_atomic_store(nxt + (size_t)bb1 * HCAT + hcol, ep1 | (unsigned)hb1,
                       __ATOMIC_RELAXED, __HIP_MEMORY_SCOPE_AGENT);

    // off-critical-path: hs stores + gx(t+1) prefetch
    hs[((size_t)bb0 * TC + t) * HCAT + hcol] = hb0;
    hs[((size_t)bb1 * TC + t) * HCAT + hcol] = hb1;
    if (t + 1 < TC) {
#pragma unroll
      for (int q = 0; q < 4; ++q) {
        gxv0[q] = bf2f(gx[((size_t)bb0 * TC + t + 1) * G4 + (size_t)q * HL + u0 + u]);
        gxv1[q] = bf2f(gx[((size_t)bb1 * TC + t + 1) * G4 + (size_t)q * HL + u0 + u]);
      }
    }
  }
  cbuf[(size_t)bb0 * HCAT + hcol] = c0;
  cbuf[(size_t)bb1 * HCAT + hcol] = c1;
}

__global__ __launch_bounds__(256, 1) void k_lstm(
    const float* __restrict__ Whh0, const float* __restrict__ Whh1,
    const float* __restrict__ Whh2,
    const ushort_t* __restrict__ gx0, const ushort_t* __restrict__ gx1,
    const ushort_t* __restrict__ gx2,
    unsigned* __restrict__ hb2, float* __restrict__ cbuf,
    ushort_t* __restrict__ hs,
    int t0, int TC)
{
  __shared__ ushort_t htile[16 * 520];
  __shared__ float gbuf[4][16][34];
  const int g    = blockIdx.x & 7;
  const int rank = blockIdx.x >> 3;        // 0..31
  if (rank < 16) {
    lstm_body<512>(Whh0, gx0, hb2, cbuf, hs, htile, gbuf,
                   g, rank * 32, 0, t0, TC);
  } else if (rank < 24) {
    lstm_body<256>(Whh1, gx1, hb2, cbuf, hs, htile, gbuf,
                   g, (rank - 16) * 32, 512, t0, TC);
  } else {
    lstm_body<256>(Whh2, gx2, hb2, cbuf, hs, htile, gbuf,
                   g, (rank - 24) * 32, 768, t0, TC);
  }
}

// fallback if workspace is too small: distinctive sentinel
__global__ void k_fill(float* __restrict__ out, int n, float v) {
  int i = blockIdx.x * 256 + threadIdx.x;
  if (i < n) out[i] = v;
}

extern "C" void kernel_launch(void* const* d_in, const int* in_sizes, int n_in,
                              void* d_out, int out_size, void* d_ws, size_t ws_size,
                              hipStream_t stream) {
  (void)in_sizes; (void)n_in;
  const float* x0  = (const float*)d_in[0];
  const float* x1  = (const float*)d_in[1];
  const float* x2  = (const float*)d_in[2];
  const float* Wih0 = (const float*)d_in[3];
  const float* Whh0 = (const float*)d_in[4];
  const float* bih0 = (const float*)d_in[5];
  const float* bhh0 = (const float*)d_in[6];
  const float* Wih1 = (const float*)d_in[7];
  const float* Whh1 = (const float*)d_in[8];
  const float* bih1 = (const float*)d_in[9];
  const float* bhh1 = (const float*)d_in[10];
  const float* Wih2 = (const float*)d_in[11];
  const float* Whh2 = (const float*)d_in[12];
  const float* bih2 = (const float*)d_in[13];
  const float* bhh2 = (const float*)d_in[14];
  const float* W1 = (const float*)d_in[15];
  const float* b1 = (const float*)d_in[16];
  const float* W2 = (const float*)d_in[17];
  const float* b2 = (const float*)d_in[18];
  float* out = (float*)d_out;

  const size_t szHbuf  = (size_t)2 * NB * HCAT * 4;   // u32 epoch|bf16, dbuf
  const size_t szCbuf  = (size_t)NB * HCAT * 4;
  const size_t szWb0   = (size_t)2048 * KP0 * 2;
  const size_t szWb1   = (size_t)1024 * KP1 * 2;
  const size_t szWb2   = (size_t)1024 * KP2 * 2;
  const size_t szW1b   = (size_t)256 * 1024 * 2;

  const int cands[6] = {256, 128, 64, 32, 16, 8};
  int TC = 0;
  for (int ci = 0; ci < 6; ++ci) {
    int tc = cands[ci];
    size_t rows = (size_t)NB * tc;
    size_t o = 0;
    auto al = [&](size_t bytes) { o += (bytes + 255) & ~(size_t)255; };
    al(szHbuf); al(szCbuf);
    al(szWb0); al(szWb1); al(szWb2); al(szW1b);
    al(rows * HCAT * 2);                // hs chunk
    al(rows * 256 * 4);                 // z chunk
    al(rows * 2048 * 2);                // gx0 chunk
    al(rows * 1024 * 2);                // gx1 chunk
    al(rows * 1024 * 2);                // gx2 chunk
    al(rows * KP0 * 2);                 // xb0
    al(rows * KP1 * 2);                 // xb1
    al(rows * KP2 * 2);                 // xb2
    if (o <= ws_size) { TC = tc; break; }
  }
  if (TC == 0) {
    k_fill<<<dim3((out_size + 255) / 256), dim3(256), 0, stream>>>(out, out_size, -8888.f);
    return;
  }
  const int tcShift = __builtin_ctz(TC);
  const size_t rows = (size_t)NB * TC;

  char* ws = (char*)d_ws;
  size_t off = 0;
  auto alloc = [&](size_t bytes) -> void* {
    void* p = ws + off;
    off += (bytes + 255) & ~(size_t)255;
    return p;
  };
  unsigned* hb2  = (unsigned*)alloc(szHbuf);
  float* cbuf    = (float*)alloc(szCbuf);
  size_t staticEnd = off;
  ushort_t* wb0  = (ushort_t*)alloc(szWb0);
  ushort_t* wb1  = (ushort_t*)alloc(szWb1);
  ushort_t* wb2  = (ushort_t*)alloc(szWb2);
  ushort_t* w1b  = (ushort_t*)alloc(szW1b);
  ushort_t* hs   = (ushort_t*)alloc(rows * HCAT * 2);
  float* z       = (float*)alloc(rows * 256 * 4);
  ushort_t* gx0  = (ushort_t*)alloc(rows * 2048 * 2);
  ushort_t* gx1  = (ushort_t*)alloc(rows * 1024 * 2);
  ushort_t* gx2  = (ushort_t*)alloc(rows * 1024 * 2);
  ushort_t* xb0  = (ushort_t*)alloc(rows * KP0 * 2);
  ushort_t* xb1  = (ushort_t*)alloc(rows * KP1 * 2);
  ushort_t* xb2  = (ushort_t*)alloc(rows * KP2 * 2);

  hipMemsetAsync(ws, 0, staticEnd, stream);   // epoch 0 == h(0) == 0, c(0) == 0

  dim3 blk(256);
  // merged weight convert: one launch for all four weight buffers
  {
    const int totW = 2048 * KP0 + 1024 * KP1 + 1024 * KP2 + 256 * 1024;
    k_cvt_w4<<<dim3((totW + 255) / 256), blk, 0, stream>>>(
        Wih0, Wih1, Wih2, W1, wb0, wb1, wb2, w1b);
  }

  const int rb  = (int)(rows / 64);    // 64-row blocks per chunk
  const int rbm = (int)(rows / 128);   // 128-row blocks per chunk
  for (int t0 = 0; t0 < NT; t0 += TC) {
    // merged x convert: one launch for all three inputs
    {
      const int totX = (int)(rows * (KP0 + KP1 + KP2));
      k_cvt_x3<<<dim3((totX + 255) / 256), blk, 0, stream>>>(
          x0, x1, x2, xb0, xb1, xb2, t0, tcShift, (int)rows);
    }

    // gx0: K=320 -> 128^2 tile (5 K-chunks amortize the bigger prologue)
    k_gemm128<<<dim3(rbm, 2048 / 128), blk, 0, stream>>>(xb0, wb0, KP0, bih0, bhh0, gx0, nullptr, 2048, 0);
    // gx1/gx2: K=128/64 -> keep 64^2 (prologue-dominated at 128^2)
    k_gemm<<<dim3(rb, 1024 / 64), blk, 0, stream>>>(xb1, wb1, KP1, bih1, bhh1, gx1, nullptr, 1024, 0);
    k_gemm<<<dim3(rb, 1024 / 64), blk, 0, stream>>>(xb2, wb2, KP2, bih2, bhh2, gx2, nullptr, 1024, 0);

    k_lstm<<<dim3(256), blk, 0, stream>>>(Whh0, Whh1, Whh2,
                                          gx0, gx1, gx2,
                                          hb2, cbuf, hs, t0, TC);

    // fc1: K=1024 -> 128^2 tile (16 K-chunks, N=256 = exactly 2 col-blocks)
    k_gemm128<<<dim3(rbm, 256 / 128), blk, 0, stream>>>(hs, w1b, 1024, b1, nullptr, nullptr, z, 256, 1);
    k_fc2<<<dim3((int)(rows / 4)), blk, 0, stream>>>(z, W2, b2, out, t0, tcShift);
  }
}

// Round 10
// 883.663 us; speedup vs baseline: 1.2561x; 1.0123x over previous
//
#include <hip/hip_runtime.h>
#include <hip/hip_bf16.h>
#include <math.h>

typedef __hip_bfloat16 bf16;
typedef unsigned short ushort_t;
typedef unsigned long long ull_t;
typedef __attribute__((ext_vector_type(8))) short short8;
typedef __attribute__((ext_vector_type(4))) float f32x4;

constexpr int NB = 128;      // batch
constexpr int NT = 256;      // time
constexpr int HCAT = 1024;   // 512+256+256
// padded K for bf16 GEMM operands (multiples of 64)
constexpr int KP0 = 320;     // 300
constexpr int KP1 = 128;     // 74
constexpr int KP2 = 64;      // 35

__device__ inline float bf2f(ushort_t u) {
  union { unsigned i; float f; } x; x.i = (unsigned)u << 16; return x.f;
}
__device__ inline ushort_t f2bf(float f) {
  bf16 b = __float2bfloat16(f);
  return *reinterpret_cast<ushort_t*>(&b);
}
// fast sigmoid/tanh via v_exp + v_rcp; saturate correctly at +-inf, no NaN.
__device__ inline float fsig(float x) {
  return __builtin_amdgcn_rcpf(1.f + __expf(-x));
}
__device__ inline float ftanh(float x) {
  return 2.f * __builtin_amdgcn_rcpf(1.f + __expf(-2.f * x)) - 1.f;
}

// ---------------------------------------------------------------------------
// merged weight convert (ONE launch): 7 fp32 weight tensors -> bf16.
// w0..w2 = Wih0..2 (zero-padded to KP), w3 = fc_W1 (K==KP), w4..w6 = Whh0..2
// (K==KP; consumed by k_lstm's prologue as bf16 short8 vector loads).
// ---------------------------------------------------------------------------
__global__ __launch_bounds__(256) void k_cvt_w7(
    const float* __restrict__ w0, const float* __restrict__ w1,
    const float* __restrict__ w2, const float* __restrict__ w3,
    const float* __restrict__ w4, const float* __restrict__ w5,
    const float* __restrict__ w6,
    ushort_t* __restrict__ o0, ushort_t* __restrict__ o1,
    ushort_t* __restrict__ o2, ushort_t* __restrict__ o3,
    ushort_t* __restrict__ o4, ushort_t* __restrict__ o5,
    ushort_t* __restrict__ o6)
{
  constexpr int T0 = 2048 * KP0;            // Wih0: 2048 x 300 -> 320
  constexpr int T1 = 1024 * KP1;            // Wih1: 1024 x 74  -> 128
  constexpr int T2 = 1024 * KP2;            // Wih2: 1024 x 35  -> 64
  constexpr int T3 = 256 * 1024;            // fc_W1 (no pad)
  constexpr int T4 = 2048 * 512;            // Whh0 (no pad)
  constexpr int T5 = 1024 * 256;            // Whh1 (no pad)
  constexpr int T6 = 1024 * 256;            // Whh2 (no pad)
  constexpr int E0 = T0, E1 = E0 + T1, E2 = E1 + T2, E3 = E2 + T3;
  constexpr int E4 = E3 + T4, E5 = E4 + T5, E6 = E5 + T6;
  int i = blockIdx.x * 256 + threadIdx.x;
  if (i < E0) {
    int r = i / KP0, k = i - r * KP0;
    o0[i] = (k < 300) ? f2bf(w0[(size_t)r * 300 + k]) : (ushort_t)0;
  } else if (i < E1) {
    int j = i - E0;
    int r = j / KP1, k = j - r * KP1;
    o1[j] = (k < 74) ? f2bf(w1[(size_t)r * 74 + k]) : (ushort_t)0;
  } else if (i < E2) {
    int j = i - E1;
    int r = j / KP2, k = j - r * KP2;
    o2[j] = (k < 35) ? f2bf(w2[(size_t)r * 35 + k]) : (ushort_t)0;
  } else if (i < E3) {
    int j = i - E2;
    o3[j] = f2bf(w3[j]);
  } else if (i < E4) {
    int j = i - E3;
    o4[j] = f2bf(w4[j]);
  } else if (i < E5) {
    int j = i - E4;
    o5[j] = f2bf(w5[j]);
  } else if (i < E6) {
    int j = i - E5;
    o6[j] = f2bf(w6[j]);
  }
}

// ---------------------------------------------------------------------------
// merged x convert (one launch per chunk): 3 fp32 x[B][NT][d] -> bf16
// [rows][KP] (row = b*TC+tl), zero-padded.
// ---------------------------------------------------------------------------
__global__ __launch_bounds__(256) void k_cvt_x3(
    const float* __restrict__ x0, const float* __restrict__ x1,
    const float* __restrict__ x2,
    ushort_t* __restrict__ o0, ushort_t* __restrict__ o1,
    ushort_t* __restrict__ o2,
    int t0, int tcShift, int rows)
{
  const int tot0 = rows * KP0;
  const int tot1 = rows * KP1;
  const int tot2 = rows * KP2;
  int i = blockIdx.x * 256 + threadIdx.x;
  if (i < tot0) {
    int row = i / KP0, k = i - row * KP0;
    int b = row >> tcShift, tl = row & ((1 << tcShift) - 1);
    o0[i] = (k < 300) ? f2bf(x0[((size_t)b * NT + t0 + tl) * 300 + k]) : (ushort_t)0;
  } else if (i < tot0 + tot1) {
    int j = i - tot0;
    int row = j / KP1, k = j - row * KP1;
    int b = row >> tcShift, tl = row & ((1 << tcShift) - 1);
    o1[j] = (k < 74) ? f2bf(x1[((size_t)b * NT + t0 + tl) * 74 + k]) : (ushort_t)0;
  } else if (i < tot0 + tot1 + tot2) {
    int j = i - tot0 - tot1;
    int row = j / KP2, k = j - row * KP2;
    int b = row >> tcShift, tl = row & ((1 << tcShift) - 1);
    o2[j] = (k < 35) ? f2bf(x2[((size_t)b * NT + t0 + tl) * 35 + k]) : (ushort_t)0;
  }
}

// ---------------------------------------------------------------------------
// Merged gx1+gx2 GEMM (one launch): 64x64 tile, BK=64, dbuf LDS — the
// R9-proven k_gemm body; blockIdx.y<16 -> layer1 (KP=128), else layer2
// (KP=64). Selection is wave-uniform per block (no divergence); math
// identical to the two separate launches it replaces.
// ---------------------------------------------------------------------------
__global__ __launch_bounds__(256) void k_gemm_gx12(
    const ushort_t* __restrict__ A1, const ushort_t* __restrict__ B1,
    const ushort_t* __restrict__ A2, const ushort_t* __restrict__ B2,
    const float* __restrict__ bi1, const float* __restrict__ bh1,
    const float* __restrict__ bi2, const float* __restrict__ bh2,
    ushort_t* __restrict__ o1, ushort_t* __restrict__ o2)
{
  __shared__ ushort_t As[2][64][72];
  __shared__ ushort_t Bs[2][64][72];
  const int by   = blockIdx.y;
  const bool l2  = (by >= 16);
  const ushort_t* A = l2 ? A2 : A1;
  const ushort_t* B = l2 ? B2 : B1;
  const float* bias0 = l2 ? bi2 : bi1;
  const float* bias1 = l2 ? bh2 : bh1;
  ushort_t* outb = l2 ? o2 : o1;
  const int KP   = l2 ? KP2 : KP1;
  const int row0 = blockIdx.x * 64;
  const int col0 = (l2 ? by - 16 : by) * 64;
  const int ldc  = 1024;
  const int tid  = threadIdx.x;
  const int lane = tid & 63;
  const int w    = tid >> 6;
  const int n    = lane & 15;
  const int quad = lane >> 4;
  const int sr = tid >> 2;           // staging row 0..63
  const int sc = (tid & 3) * 16;     // staging col (elems)

  const ushort_t* arow = A + (size_t)(row0 + sr) * KP + sc;
  const ushort_t* brow = B + (size_t)(col0 + sr) * KP + sc;

  short8 ra0 = *reinterpret_cast<const short8*>(arow);
  short8 ra1 = *reinterpret_cast<const short8*>(arow + 8);
  short8 rb0 = *reinterpret_cast<const short8*>(brow);
  short8 rb1 = *reinterpret_cast<const short8*>(brow + 8);
  *reinterpret_cast<short8*>(&As[0][sr][sc])     = ra0;
  *reinterpret_cast<short8*>(&As[0][sr][sc + 8]) = ra1;
  *reinterpret_cast<short8*>(&Bs[0][sr][sc])     = rb0;
  *reinterpret_cast<short8*>(&Bs[0][sr][sc + 8]) = rb1;

  f32x4 acc[4] = {{0,0,0,0},{0,0,0,0},{0,0,0,0},{0,0,0,0}};
  const int nch = KP >> 6;
  for (int ch = 0; ch < nch; ++ch) {
    __syncthreads();
    const int cur = ch & 1;
    if (ch + 1 < nch) {
      const ushort_t* an = arow + (ch + 1) * 64;
      const ushort_t* bn = brow + (ch + 1) * 64;
      ra0 = *reinterpret_cast<const short8*>(an);
      ra1 = *reinterpret_cast<const short8*>(an + 8);
      rb0 = *reinterpret_cast<const short8*>(bn);
      rb1 = *reinterpret_cast<const short8*>(bn + 8);
    }
#pragma unroll
    for (int kc = 0; kc < 2; ++kc) {
      short8 bfr = *reinterpret_cast<const short8*>(&Bs[cur][w * 16 + n][quad * 8 + kc * 32]);
#pragma unroll
      for (int mt = 0; mt < 4; ++mt) {
        short8 afr = *reinterpret_cast<const short8*>(&As[cur][mt * 16 + n][quad * 8 + kc * 32]);
        acc[mt] = __builtin_amdgcn_mfma_f32_16x16x32_bf16(afr, bfr, acc[mt], 0, 0, 0);
      }
    }
    if (ch + 1 < nch) {
      const int nxt = 1 - cur;
      *reinterpret_cast<short8*>(&As[nxt][sr][sc])     = ra0;
      *reinterpret_cast<short8*>(&As[nxt][sr][sc + 8]) = ra1;
      *reinterpret_cast<short8*>(&Bs[nxt][sr][sc])     = rb0;
      *reinterpret_cast<short8*>(&Bs[nxt][sr][sc + 8]) = rb1;
    }
  }

  const int col = col0 + w * 16 + n;
  const float bsum = bias0[col] + bias1[col];
#pragma unroll
  for (int mt = 0; mt < 4; ++mt)
#pragma unroll
    for (int r = 0; r < 4; ++r) {
      int row = row0 + mt * 16 + quad * 4 + r;
      outb[(size_t)row * ldc + col] = f2bf(acc[mt][r] + bsum);
    }
}

// ---------------------------------------------------------------------------
// 128x128-tile bf16 B^T GEMM (R2 harness-verified, ladder step-2 structure):
// BK=64, reg-prefetch + dbuf LDS, 1 barrier/chunk; 4 waves each own a 64x64
// quadrant (4x4 frags). Used ONLY where K is large enough to amortize the
// bigger prologue: gx0 (K=320) and fc1 (K=1024).  [R17: -22us vs all-64^2]
// ---------------------------------------------------------------------------
__global__ __launch_bounds__(256) void k_gemm128(
    const ushort_t* __restrict__ A, const ushort_t* __restrict__ B, int KP,
    const float* __restrict__ bias0, const float* __restrict__ bias1,
    ushort_t* __restrict__ outb, float* __restrict__ outf, int ldc, int mode)
{
  __shared__ ushort_t As[2][128][72];
  __shared__ ushort_t Bs[2][128][72];
  const int row0 = blockIdx.x * 128;
  const int col0 = blockIdx.y * 128;
  const int tid  = threadIdx.x;
  const int lane = tid & 63;
  const int w    = tid >> 6;
  const int wr   = w >> 1;             // wave quadrant row
  const int wc   = w & 1;              // wave quadrant col
  const int n    = lane & 15;
  const int quad = lane >> 4;
  const int sr = tid >> 1;             // staging row 0..127
  const int sc = (tid & 1) * 32;       // staging col (elems)

  const ushort_t* arow = A + (size_t)(row0 + sr) * KP + sc;
  const ushort_t* brow = B + (size_t)(col0 + sr) * KP + sc;

  short8 ra[4], rb[4];
#pragma unroll
  for (int j = 0; j < 4; ++j) {
    ra[j] = *reinterpret_cast<const short8*>(arow + j * 8);
    rb[j] = *reinterpret_cast<const short8*>(brow + j * 8);
  }
#pragma unroll
  for (int j = 0; j < 4; ++j) {
    *reinterpret_cast<short8*>(&As[0][sr][sc + j * 8]) = ra[j];
    *reinterpret_cast<short8*>(&Bs[0][sr][sc + j * 8]) = rb[j];
  }

  f32x4 acc[4][4] = {};
  const int nch = KP >> 6;
  for (int ch = 0; ch < nch; ++ch) {
    __syncthreads();
    const int cur = ch & 1;
    if (ch + 1 < nch) {
      const ushort_t* an = arow + (ch + 1) * 64;
      const ushort_t* bn = brow + (ch + 1) * 64;
#pragma unroll
      for (int j = 0; j < 4; ++j) {
        ra[j] = *reinterpret_cast<const short8*>(an + j * 8);
        rb[j] = *reinterpret_cast<const short8*>(bn + j * 8);
      }
    }
#pragma unroll
    for (int kc = 0; kc < 2; ++kc) {
      short8 bfr[4];
#pragma unroll
      for (int nt = 0; nt < 4; ++nt)
        bfr[nt] = *reinterpret_cast<const short8*>(
            &Bs[cur][wc * 64 + nt * 16 + n][quad * 8 + kc * 32]);
#pragma unroll
      for (int mt = 0; mt < 4; ++mt) {
        short8 afr = *reinterpret_cast<const short8*>(
            &As[cur][wr * 64 + mt * 16 + n][quad * 8 + kc * 32]);
#pragma unroll
        for (int nt = 0; nt < 4; ++nt)
          acc[mt][nt] = __builtin_amdgcn_mfma_f32_16x16x32_bf16(afr, bfr[nt], acc[mt][nt], 0, 0, 0);
      }
    }
    if (ch + 1 < nch) {
      const int nxt = 1 - cur;
#pragma unroll
      for (int j = 0; j < 4; ++j) {
        *reinterpret_cast<short8*>(&As[nxt][sr][sc + j * 8]) = ra[j];
        *reinterpret_cast<short8*>(&Bs[nxt][sr][sc + j * 8]) = rb[j];
      }
    }
  }

#pragma unroll
  for (int nt = 0; nt < 4; ++nt) {
    const int col = col0 + wc * 64 + nt * 16 + n;
    if (mode == 0) {
      const float bsum = bias0[col] + bias1[col];
#pragma unroll
      for (int mt = 0; mt < 4; ++mt)
#pragma unroll
        for (int r = 0; r < 4; ++r) {
          int row = row0 + wr * 64 + mt * 16 + quad * 4 + r;
          outb[(size_t)row * ldc + col] = f2bf(acc[mt][nt][r] + bsum);
        }
    } else {
      const float bsum = bias0[col];
#pragma unroll
      for (int mt = 0; mt < 4; ++mt)
#pragma unroll
        for (int r = 0; r < 4; ++r) {
          int row = row0 + wr * 64 + mt * 16 + quad * 4 + r;
          outf[(size_t)row * ldc + col] = fmaxf(acc[mt][nt][r] + bsum, 0.f);
        }
    }
  }
}

// ---------------------------------------------------------------------------
// fc2 + log_softmax: one wave per chunk row; map chunk row -> global (b,t)
// ---------------------------------------------------------------------------
__global__ __launch_bounds__(256) void k_fc2(
    const float* __restrict__ Z, const float* __restrict__ W2,
    const float* __restrict__ b2, float* __restrict__ out, int t0, int tcShift)
{
  const int wave = threadIdx.x >> 6;
  const int lane = threadIdx.x & 63;
  const int bt = blockIdx.x * 4 + wave;
  const float* z = Z + (size_t)bt * 256;
  float zv[4];
#pragma unroll
  for (int j = 0; j < 4; ++j) zv[j] = z[lane + 64 * j];
  float lg[7];
#pragma unroll
  for (int o = 0; o < 7; ++o) {
    float a = 0.f;
#pragma unroll
    for (int j = 0; j < 4; ++j) a += zv[j] * W2[o * 256 + lane + 64 * j];
#pragma unroll
    for (int off = 32; off > 0; off >>= 1) a += __shfl_down(a, off, 64);
    lg[o] = a;   // valid on lane 0
  }
  if (lane == 0) {
    const int b = bt >> tcShift;
    const int tl = bt & ((1 << tcShift) - 1);
    float* op = out + ((size_t)b * NT + t0 + tl) * 7;
    float lo[7];
    float m = -1e30f;
#pragma unroll
    for (int o = 0; o < 7; ++o) { lo[o] = lg[o] + b2[o]; m = fmaxf(m, lo[o]); }
    float s = 0.f;
#pragma unroll
    for (int o = 0; o < 7; ++o) s += expf(lo[o] - m);
    float lse = m + logf(s);
#pragma unroll
    for (int o = 0; o < 7; ++o) op[o] = lo[o] - lse;
  }
}

// ---------------------------------------------------------------------------
// Recurrent kernel R11 — step loop VERBATIM (~285-291us/dispatch measured).
// Epoch-packed h words ((epoch<<16)|bf16): data is its own flag; 2-buffer by
// step parity; relaxed agent-scope atomics; 2 barriers/step. DO NOT touch the
// poll/publish/epilogue ordering: the epilogue's gx loads+bf2f waits act as a
// calibrated backoff so the first sweep usually passes (R12/R14/R15/R16 all
// perturbed this window and regressed 17-53%).
// R19 change (prologue only): Whh arrives pre-converted bf16 -> wfrag loads
// are short8 vector loads (was 256 scalar fp32 loads + f2bf per thread).
// Identical numerics (same f2bf rounding, applied once in k_cvt_w7).
// ---------------------------------------------------------------------------
template<int HL>
__device__ void lstm_body(const ushort_t* __restrict__ Whh,  // bf16 [4*HL][HL]
                          const ushort_t* __restrict__ gx,   // bf16 bits, [NB][TC][4*HL]
                          unsigned* __restrict__ hb2,        // u32 [2][NB][HCAT] = epoch|bf16
                          float* __restrict__ cbuf,          // fp32 [NB][HCAT]
                          ushort_t* __restrict__ hs,         // bf16 [NB][TC][HCAT]
                          ushort_t* htile,                   // LDS [16][HL+8]
                          float (*gbuf)[16][34],             // LDS gate tiles
                          int g, int u0, int hoff, int t0, int TC)
{
  constexpr int KC  = HL / 32;
  constexpr int LHP = HL + 8;          // padded LDS row, bf16 units
  constexpr int NGR = HL / 32;         // 8-byte source granules per thread
  const int tid  = threadIdx.x;
  const int lane = tid & 63;
  const int wgate = tid >> 6;          // wave index == gate (i,f,g,o)
  const int n    = lane & 15;
  const int quad = lane >> 4;

  short8 wfrag[2][KC];
#pragma unroll
  for (int tau = 0; tau < 2; ++tau) {
    const ushort_t* wrow = Whh + ((size_t)wgate * HL + u0 + 16 * tau + n) * HL + quad * 8;
#pragma unroll
    for (int kc = 0; kc < KC; ++kc)
      wfrag[tau][kc] = *reinterpret_cast<const short8*>(wrow + kc * 32);
  }

  const int u  = tid & 31;
  const int bh = tid >> 5;             // 0..7
  const int bb0 = g * 16 + bh;
  const int bb1 = bb0 + 8;
  const int hcol = hoff + u0 + u;
  float c0 = cbuf[(size_t)bb0 * HCAT + hcol];
  float c1 = cbuf[(size_t)bb1 * HCAT + hcol];

  const int srow = wgate * 4 + (lane >> 4);   // 0..15
  const int scol = lane & 15;
  unsigned* htile32 = reinterpret_cast<unsigned*>(htile);

  const size_t G4 = (size_t)(4 * HL);
  float gxv0[4], gxv1[4];
#pragma unroll
  for (int q = 0; q < 4; ++q) {
    gxv0[q] = bf2f(gx[((size_t)bb0 * TC) * G4 + (size_t)q * HL + u0 + u]);
    gxv1[q] = bf2f(gx[((size_t)bb1 * TC) * G4 + (size_t)q * HL + u0 + u]);
  }

  const ull_t EPM = 0xFFFF0000FFFF0000ull;

  for (int t = 0; t < TC; ++t) {
    const unsigned ep = (unsigned)(t0 + t);
    const ull_t want = ((ull_t)ep << 16) | ((ull_t)ep << 48);
    const ull_t* src64 = reinterpret_cast<const ull_t*>(
        hb2 + ((size_t)(ep & 1) * NB + g * 16 + srow) * HCAT + hoff);

    // per-thread poll: loads return payload+epoch together; a sweep issues all
    // NGR loads back-to-back (waits batched), so one sweep costs ~1 LLC latency
    ull_t vv[NGR];
    while (true) {
#pragma unroll
      for (int i = 0; i < NGR; ++i)
        vv[i] = __hip_atomic_load(src64 + scol + i * 16,
                                  __ATOMIC_RELAXED, __HIP_MEMORY_SCOPE_AGENT);
      ull_t bad = 0;
#pragma unroll
      for (int i = 0; i < NGR; ++i) bad |= (vv[i] ^ want) & EPM;
      if (bad == 0) break;
      __builtin_amdgcn_s_sleep(1);
    }
#pragma unroll
    for (int i = 0; i < NGR; ++i)
      htile32[srow * (LHP / 2) + scol + i * 16] =
          (unsigned)(vv[i] & 0xffffu) | ((unsigned)(vv[i] >> 16) & 0xffff0000u);
    __syncthreads();   // htile complete (also orders prev-step gbuf reads vs writes)

    f32x4 acc0 = {0.f, 0.f, 0.f, 0.f};
    f32x4 acc1 = {0.f, 0.f, 0.f, 0.f};
#pragma unroll
    for (int kc = 0; kc < KC; ++kc) {
      short8 a = *reinterpret_cast<const short8*>(htile + n * LHP + quad * 8 + kc * 32);
      acc0 = __builtin_amdgcn_mfma_f32_16x16x32_bf16(a, wfrag[0][kc], acc0, 0, 0, 0);
      acc1 = __builtin_amdgcn_mfma_f32_16x16x32_bf16(a, wfrag[1][kc], acc1, 0, 0, 0);
    }
#pragma unroll
    for (int r = 0; r < 4; ++r) {
      gbuf[wgate][quad * 4 + r][n]      = acc0[r];
      gbuf[wgate][quad * 4 + r][16 + n] = acc1[r];
    }
    __syncthreads();   // gbuf ready (also ensures all htile reads done)

    float pi0 = gbuf[0][bh][u] + gxv0[0];
    float pf0 = gbuf[1][bh][u] + gxv0[1];
    float pg0 = gbuf[2][bh][u] + gxv0[2];
    float po0 = gbuf[3][bh][u] + gxv0[3];
    float pi1 = gbuf[0][bh + 8][u] + gxv1[0];
    float pf1 = gbuf[1][bh + 8][u] + gxv1[1];
    float pg1 = gbuf[2][bh + 8][u] + gxv1[2];
    float po1 = gbuf[3][bh + 8][u] + gxv1[3];

    float si0 = fsig(pi0), sf0 = fsig(pf0), so0 = fsig(po0);
    float tg0 = ftanh(pg0);
    c0 = sf0 * c0 + si0 * tg0;
    float h0 = so0 * ftanh(c0);
    float si1 = fsig(pi1), sf1 = fsig(pf1), so1 = fsig(po1);
    float tg1 = ftanh(pg1);
    c1 = sf1 * c1 + si1 * tg1;
    float h1 = so1 * ftanh(c1);

    // publish h(t+1): payload and validity in one atomic 4B word — no fence,
    // no drain, no flag. Issued immediately; everything after is off-path.
    const ushort_t hb0 = f2bf(h0), hb1 = f2bf(h1);
    const unsigned ep1 = (ep + 1) << 16;
    unsigned* nxt = hb2 + (size_t)((ep + 1) & 1) * NB * HCAT;
    __hip_atomic_store(nxt + (size_t)bb0 * HCAT + hcol, ep1 | (unsigned)hb0,
                       __ATOMIC_RELAXED, __HIP_MEMORY_SCOPE_AGENT);
    __hip_atomic_store(nxt + (size_t)bb1 * HCAT + hcol, ep1 | (unsigned)hb1,
                       __ATOMIC_RELAXED, __HIP_MEMORY_SCOPE_AGENT);

    // off-critical-path: hs stores + gx(t+1) prefetch
    hs[((size_t)bb0 * TC + t) * HCAT + hcol] = hb0;
    hs[((size_t)bb1 * TC + t) * HCAT + hcol] = hb1;
    if (t + 1 < TC) {
#pragma unroll
      for (int q = 0; q < 4; ++q) {
        gxv0[q] = bf2f(gx[((size_t)bb0 * TC + t + 1) * G4 + (size_t)q * HL + u0 + u]);
        gxv1[q] = bf2f(gx[((size_t)bb1 * TC + t + 1) * G4 + (size_t)q * HL + u0 + u]);
      }
    }
  }
  cbuf[(size_t)bb0 * HCAT + hcol] = c0;
  cbuf[(size_t)bb1 * HCAT + hcol] = c1;
}

__global__ __launch_bounds__(256, 1) void k_lstm(
    const ushort_t* __restrict__ Whh0, const ushort_t* __restrict__ Whh1,
    const ushort_t* __restrict__ Whh2,
    const ushort_t* __restrict__ gx0, const ushort_t* __restrict__ gx1,
    const ushort_t* __restrict__ gx2,
    unsigned* __restrict__ hb2, float* __restrict__ cbuf,
    ushort_t* __restrict__ hs,
    int t0, int TC)
{
  __shared__ ushort_t htile[16 * 520];
  __shared__ float gbuf[4][16][34];
  const int g    = blockIdx.x & 7;
  const int rank = blockIdx.x >> 3;        // 0..31
  if (rank < 16) {
    lstm_body<512>(Whh0, gx0, hb2, cbuf, hs, htile, gbuf,
                   g, rank * 32, 0, t0, TC);
  } else if (rank < 24) {
    lstm_body<256>(Whh1, gx1, hb2, cbuf, hs, htile, gbuf,
                   g, (rank - 16) * 32, 512, t0, TC);
  } else {
    lstm_body<256>(Whh2, gx2, hb2, cbuf, hs, htile, gbuf,
                   g, (rank - 24) * 32, 768, t0, TC);
  }
}

// fallback if workspace is too small: distinctive sentinel
__global__ void k_fill(float* __restrict__ out, int n, float v) {
  int i = blockIdx.x * 256 + threadIdx.x;
  if (i < n) out[i] = v;
}

extern "C" void kernel_launch(void* const* d_in, const int* in_sizes, int n_in,
                              void* d_out, int out_size, void* d_ws, size_t ws_size,
                              hipStream_t stream) {
  (void)in_sizes; (void)n_in;
  const float* x0  = (const float*)d_in[0];
  const float* x1  = (const float*)d_in[1];
  const float* x2  = (const float*)d_in[2];
  const float* Wih0 = (const float*)d_in[3];
  const float* Whh0 = (const float*)d_in[4];
  const float* bih0 = (const float*)d_in[5];
  const float* bhh0 = (const float*)d_in[6];
  const float* Wih1 = (const float*)d_in[7];
  const float* Whh1 = (const float*)d_in[8];
  const float* bih1 = (const float*)d_in[9];
  const float* bhh1 = (const float*)d_in[10];
  const float* Wih2 = (const float*)d_in[11];
  const float* Whh2 = (const float*)d_in[12];
  const float* bih2 = (const float*)d_in[13];
  const float* bhh2 = (const float*)d_in[14];
  const float* W1 = (const float*)d_in[15];
  const float* b1 = (const float*)d_in[16];
  const float* W2 = (const float*)d_in[17];
  const float* b2 = (const float*)d_in[18];
  float* out = (float*)d_out;

  const size_t szHbuf  = (size_t)2 * NB * HCAT * 4;   // u32 epoch|bf16, dbuf
  const size_t szCbuf  = (size_t)NB * HCAT * 4;
  const size_t szWb0   = (size_t)2048 * KP0 * 2;
  const size_t szWb1   = (size_t)1024 * KP1 * 2;
  const size_t szWb2   = (size_t)1024 * KP2 * 2;
  const size_t szW1b   = (size_t)256 * 1024 * 2;
  const size_t szWhb0  = (size_t)2048 * 512 * 2;      // bf16 Whh0
  const size_t szWhb1  = (size_t)1024 * 256 * 2;      // bf16 Whh1
  const size_t szWhb2  = (size_t)1024 * 256 * 2;      // bf16 Whh2

  const int cands[6] = {256, 128, 64, 32, 16, 8};
  int TC = 0;
  for (int ci = 0; ci < 6; ++ci) {
    int tc = cands[ci];
    size_t rows = (size_t)NB * tc;
    size_t o = 0;
    auto al = [&](size_t bytes) { o += (bytes + 255) & ~(size_t)255; };
    al(szHbuf); al(szCbuf);
    al(szWb0); al(szWb1); al(szWb2); al(szW1b);
    al(szWhb0); al(szWhb1); al(szWhb2);
    al(rows * HCAT * 2);                // hs chunk
    al(rows * 256 * 4);                 // z chunk
    al(rows * 2048 * 2);                // gx0 chunk
    al(rows * 1024 * 2);                // gx1 chunk
    al(rows * 1024 * 2);                // gx2 chunk
    al(rows * KP0 * 2);                 // xb0
    al(rows * KP1 * 2);                 // xb1
    al(rows * KP2 * 2);                 // xb2
    if (o <= ws_size) { TC = tc; break; }
  }
  if (TC == 0) {
    k_fill<<<dim3((out_size + 255) / 256), dim3(256), 0, stream>>>(out, out_size, -8888.f);
    return;
  }
  const int tcShift = __builtin_ctz(TC);
  const size_t rows = (size_t)NB * TC;

  char* ws = (char*)d_ws;
  size_t off = 0;
  auto alloc = [&](size_t bytes) -> void* {
    void* p = ws + off;
    off += (bytes + 255) & ~(size_t)255;
    return p;
  };
  unsigned* hb2  = (unsigned*)alloc(szHbuf);
  float* cbuf    = (float*)alloc(szCbuf);
  size_t staticEnd = off;
  ushort_t* wb0  = (ushort_t*)alloc(szWb0);
  ushort_t* wb1  = (ushort_t*)alloc(szWb1);
  ushort_t* wb2  = (ushort_t*)alloc(szWb2);
  ushort_t* w1b  = (ushort_t*)alloc(szW1b);
  ushort_t* whb0 = (ushort_t*)alloc(szWhb0);
  ushort_t* whb1 = (ushort_t*)alloc(szWhb1);
  ushort_t* whb2 = (ushort_t*)alloc(szWhb2);
  ushort_t* hs   = (ushort_t*)alloc(rows * HCAT * 2);
  float* z       = (float*)alloc(rows * 256 * 4);
  ushort_t* gx0  = (ushort_t*)alloc(rows * 2048 * 2);
  ushort_t* gx1  = (ushort_t*)alloc(rows * 1024 * 2);
  ushort_t* gx2  = (ushort_t*)alloc(rows * 1024 * 2);
  ushort_t* xb0  = (ushort_t*)alloc(rows * KP0 * 2);
  ushort_t* xb1  = (ushort_t*)alloc(rows * KP1 * 2);
  ushort_t* xb2  = (ushort_t*)alloc(rows * KP2 * 2);

  hipMemsetAsync(ws, 0, staticEnd, stream);   // epoch 0 == h(0) == 0, c(0) == 0

  dim3 blk(256);
  // merged weight convert: one launch for all seven weight tensors
  {
    const int totW = 2048 * KP0 + 1024 * KP1 + 1024 * KP2 + 256 * 1024
                   + 2048 * 512 + 1024 * 256 + 1024 * 256;
    k_cvt_w7<<<dim3((totW + 255) / 256), blk, 0, stream>>>(
        Wih0, Wih1, Wih2, W1, Whh0, Whh1, Whh2,
        wb0, wb1, wb2, w1b, whb0, whb1, whb2);
  }

  const int rb  = (int)(rows / 64);    // 64-row blocks per chunk
  const int rbm = (int)(rows / 128);   // 128-row blocks per chunk
  for (int t0 = 0; t0 < NT; t0 += TC) {
    // merged x convert: one launch for all three inputs
    {
      const int totX = (int)(rows * (KP0 + KP1 + KP2));
      k_cvt_x3<<<dim3((totX + 255) / 256), blk, 0, stream>>>(
          x0, x1, x2, xb0, xb1, xb2, t0, tcShift, (int)rows);
    }

    // gx0: K=320 -> 128^2 tile (5 K-chunks amortize the bigger prologue)
    k_gemm128<<<dim3(rbm, 2048 / 128), blk, 0, stream>>>(xb0, wb0, KP0, bih0, bhh0, gx0, nullptr, 2048, 0);
    // gx1+gx2 merged: one launch, 64^2 tiles, pointer select by blockIdx.y
    k_gemm_gx12<<<dim3(rb, 32), blk, 0, stream>>>(xb1, wb1, xb2, wb2,
                                                  bih1, bhh1, bih2, bhh2,
                                                  gx1, gx2);

    k_lstm<<<dim3(256), blk, 0, stream>>>(whb0, whb1, whb2,
                                          gx0, gx1, gx2,
                                          hb2, cbuf, hs, t0, TC);

    // fc1: K=1024 -> 128^2 tile (16 K-chunks, N=256 = exactly 2 col-blocks)
    k_gemm128<<<dim3(rbm, 256 / 128), blk, 0, stream>>>(hs, w1b, 1024, b1, nullptr, nullptr, z, 256, 1);
    k_fc2<<<dim3((int)(rows / 4)), blk, 0, stream>>>(z, W2, b2, out, t0, tcShift);
  }
}